// Round 13
// baseline (418.507 us; speedup 1.0000x reference)
//
#include <hip/hip_runtime.h>
#include <hip/hip_fp16.h>

constexpr int C = 128;
constexpr int N = 4096;
constexpr int B = 4;

typedef _Float16 f16x8 __attribute__((ext_vector_type(8)));
typedef _Float16 f16x4 __attribute__((ext_vector_type(4)));
typedef float    f32x4 __attribute__((ext_vector_type(4)));

// bnstat site layout: st[shard<4][256]: [c]=sum, [128+c]=sumsq.  Final coeff:
__device__ __forceinline__ float2 bn_coef(const float* __restrict__ st, int c,
                                          const float* __restrict__ gamma,
                                          const float* __restrict__ beta) {
  const float s = st[c] + st[256 + c] + st[512 + c] + st[768 + c];
  const float q = st[128 + c] + st[384 + c] + st[640 + c] + st[896 + c];
  const float inv = 1.0f / (B * N);
  const float mean = s * inv;
  const float var = q * inv - mean * mean;    // biased, like torch BN
  const float sc = gamma[c] * rsqrtf(var + 1e-5f);
  return {sc, beta[c] - mean * sc};
}

// ---------------------------------------------------------------------------
// One-shot weight convert fp32 -> f16 into workspace, concatenated:
// [w1(16K) | w2(16K) | wv(64K) | wt(64K) | wqk(16K)] elements.
// grid 176, 256 thr; each thread converts one float4.
// ---------------------------------------------------------------------------
__global__ __launch_bounds__(256) void k_wcvt(const float* __restrict__ w1,
                                              const float* __restrict__ w2,
                                              const float* __restrict__ wv,
                                              const float* __restrict__ wt,
                                              const float* __restrict__ wqk,
                                              _Float16* __restrict__ WF) {
  const int g = blockIdx.x * 256 + threadIdx.x;   // float4 index
  const float* src; int off;
  if (g < 4096)       { src = w1;  off = g; }
  else if (g < 8192)  { src = w2;  off = g - 4096; }
  else if (g < 24576) { src = wv;  off = g - 8192; }
  else if (g < 40960) { src = wt;  off = g - 24576; }
  else                { src = wqk; off = g - 40960; }
  const float4 v = ((const float4*)src)[off];
  f16x4 h = {(_Float16)v.x, (_Float16)v.y, (_Float16)v.z, (_Float16)v.w};
  *(f16x4*)&WF[(size_t)g * 4] = h;
}

// ---------------------------------------------------------------------------
// Mask compaction: exclusive prefix sum of (mask!=0) per batch + valid count.
// grid B, 1024 thr (4 elements/thread).
// ---------------------------------------------------------------------------
__global__ __launch_bounds__(1024) void k_mask(const int* __restrict__ mask,
                                               int* __restrict__ psum,
                                               int* __restrict__ nvb) {
  const int b = blockIdx.x, tid = threadIdx.x;
  __shared__ int wsum[16];
  const int4 mv = *(const int4*)&mask[b * N + tid * 4];
  const int m0 = (mv.x != 0), m1 = (mv.y != 0), m2 = (mv.z != 0), m3 = (mv.w != 0);
  const int s0 = m0, s1 = s0 + m1, s2 = s1 + m2, s3 = s2 + m3;
  const int lane = tid & 63, w = tid >> 6;
  int sc = s3;
#pragma unroll
  for (int o = 1; o < 64; o <<= 1) {
    const int v = __shfl_up(sc, o, 64);
    if (lane >= o) sc += v;
  }
  if (lane == 63) wsum[w] = sc;
  __syncthreads();
  if (tid < 16) {
    int v = wsum[tid];
#pragma unroll
    for (int o = 1; o < 16; o <<= 1) {
      const int u = __shfl_up(v, o, 64);
      if (tid >= o) v += u;
    }
    wsum[tid] = v;
  }
  __syncthreads();
  const int excl = ((w > 0) ? wsum[w - 1] : 0) + sc - s3;
  int4 pv;
  pv.x = excl; pv.y = excl + s0; pv.z = excl + s1; pv.w = excl + s2;
  *(int4*)&psum[b * N + tid * 4] = pv;
  if (tid == 0) nvb[b] = wsum[15];
}

// ---------------------------------------------------------------------------
// Stem GEMM, optionally fused with the PREVIOUS stage's BN+ReLU (FUSE_BN:
// input is f16 pre-BN T2; coefficients from st_in; stem1 activation never
// touches HBM).  Y f16 out; stats -> 4-sharded atomics in st_out.
// grid (N/64, 2, B), block 512.
// ---------------------------------------------------------------------------
template<bool FUSE_BN>
__global__ __launch_bounds__(512) void k_gwm(const _Float16* __restrict__ WF,
                                             const void* __restrict__ Xv,
                                             const float* __restrict__ st_in,
                                             const float* __restrict__ gamma,
                                             const float* __restrict__ beta,
                                             _Float16* __restrict__ Y,
                                             float* __restrict__ st_out) {
  __shared__ _Float16 XT[64 * 136];          // [n][c], stride 136 (16B-aligned rows)
  __shared__ float statP[4][64], statQ[4][64];
  __shared__ float bcS[128][2];
  const int tid = threadIdx.x;
  const int n0 = blockIdx.x * 64, oh = blockIdx.y, b = blockIdx.z;
  if constexpr (FUSE_BN) {
    if (tid < 128) {
      const float2 bc = bn_coef(st_in, tid, gamma, beta);
      bcS[tid][0] = bc.x; bcS[tid][1] = bc.y;
    }
    __syncthreads();
    const _Float16* Xb = (const _Float16*)Xv + (size_t)(b * C) * N + n0;
#pragma unroll
    for (int i = 0; i < 4; i++) {            // 2048 f16x4: c=idx>>4, q=idx&15
      const int idx = tid + i * 512;
      const int c = idx >> 4, q = idx & 15;
      const f16x4 t = *(const f16x4*)&Xb[(size_t)c * N + q * 4];
      const float sc = bcS[c][0], sh = bcS[c][1];
#pragma unroll
      for (int e = 0; e < 4; e++)
        XT[(q * 4 + e) * 136 + c] = (_Float16)fmaxf((float)t[e] * sc + sh, 0.f);
    }
  } else {
    const float* Xb = (const float*)Xv + (size_t)(b * C) * N + n0;
#pragma unroll
    for (int i = 0; i < 4; i++) {            // 2048 float4: c=idx>>4, q=idx&15
      const int idx = tid + i * 512;
      const int c = idx >> 4, q = idx & 15;
      const float4 v = *(const float4*)&Xb[(size_t)c * N + q * 4];
      XT[(q * 4 + 0) * 136 + c] = (_Float16)v.x;
      XT[(q * 4 + 1) * 136 + c] = (_Float16)v.y;
      XT[(q * 4 + 2) * 136 + c] = (_Float16)v.z;
      XT[(q * 4 + 3) * 136 + c] = (_Float16)v.w;
    }
  }
  __syncthreads();
  const int w = tid >> 6, lane = tid & 63, quad = lane >> 4, lr = lane & 15;
  const int nt = w & 3, og = w >> 2;
  const int ob[2] = {oh * 64 + og * 16, oh * 64 + (og + 2) * 16};
  f16x8 aW[2][4];
#pragma unroll
  for (int t = 0; t < 2; t++)
#pragma unroll
    for (int kc = 0; kc < 4; kc++)
      aW[t][kc] = *(const f16x8*)&WF[(size_t)(ob[t] + lr) * 128 + kc * 32 + quad * 8];
  f32x4 acc[2];
  acc[0] = (f32x4){0.f, 0.f, 0.f, 0.f};
  acc[1] = (f32x4){0.f, 0.f, 0.f, 0.f};
#pragma unroll
  for (int kc = 0; kc < 4; kc++) {
    const f16x8 bf = *(const f16x8*)&XT[(nt * 16 + lr) * 136 + kc * 32 + quad * 8];
    acc[0] = __builtin_amdgcn_mfma_f32_16x16x32_f16(aW[0][kc], bf, acc[0], 0, 0, 0);
    acc[1] = __builtin_amdgcn_mfma_f32_16x16x32_f16(aW[1][kc], bf, acc[1], 0, 0, 0);
  }
#pragma unroll
  for (int t = 0; t < 2; t++) {
#pragma unroll
    for (int r = 0; r < 4; r++) {
      const int o = ob[t] + quad * 4 + r;
      const float val = acc[t][r];
      Y[(size_t)(b * C + o) * N + n0 + nt * 16 + lr] = (_Float16)val;
      float s = val, q = val * val;
      s += __shfl_xor(s, 1, 64); q += __shfl_xor(q, 1, 64);
      s += __shfl_xor(s, 2, 64); q += __shfl_xor(q, 2, 64);
      s += __shfl_xor(s, 4, 64); q += __shfl_xor(q, 4, 64);
      s += __shfl_xor(s, 8, 64); q += __shfl_xor(q, 8, 64);
      if (lr == 0) { statP[nt][o - oh * 64] = s; statQ[nt][o - oh * 64] = q; }
    }
  }
  __syncthreads();
  if (tid < 64) {
    const int o = oh * 64 + tid;
    const float s = statP[0][tid] + statP[1][tid] + statP[2][tid] + statP[3][tid];
    const float q = statQ[0][tid] + statQ[1][tid] + statQ[2][tid] + statQ[3][tid];
    float* sh = st_out + (blockIdx.x & 3) * 256;
    atomicAdd(&sh[o], s);
    atomicAdd(&sh[128 + o], q);
  }
}

// ---------------------------------------------------------------------------
// Fused [prev-layer BN+ReLU(+residual)+Out] + XV/QT projection.
// Staging computes h = relu(bn(T2)) (+H_old), writes H (+Out slice), then
// projects h.  Outputs: QT/QTc/XVc/xvp as before.
// grid (N/32, B), block 256.
// ---------------------------------------------------------------------------
template<bool RES>
__global__ __launch_bounds__(256) void k_qvF(const _Float16* __restrict__ WFv,
                                             const _Float16* __restrict__ WFqk,
                                             const _Float16* __restrict__ T2,
                                             const float* __restrict__ st_in,
                                             const float* __restrict__ gamma,
                                             const float* __restrict__ beta,
                                             float* __restrict__ H,
                                             float* __restrict__ OutS,
                                             const float* __restrict__ bv,
                                             const int* __restrict__ mask,
                                             const int* __restrict__ psum,
                                             _Float16* __restrict__ XVc,
                                             _Float16* __restrict__ QT,
                                             _Float16* __restrict__ QTc,
                                             float* __restrict__ xvp) {
  __shared__ _Float16 XT[32 * 136];
  __shared__ float SP[2][128];
  __shared__ float bcS[128][2];
  const int tid = threadIdx.x;
  const int n0 = blockIdx.x * 32, b = blockIdx.y;
  if (tid < 128) {
    const float2 bc = bn_coef(st_in, tid, gamma, beta);
    bcS[tid][0] = bc.x; bcS[tid][1] = bc.y;
  }
  __syncthreads();
  const _Float16* Tb = T2 + (size_t)(b * C) * N + n0;
#pragma unroll
  for (int i = 0; i < 4; i++) {              // 1024 quads: c=idx>>3, q=idx&7
    const int idx = tid + i * 256;
    const int c = idx >> 3, q = idx & 7;
    const f16x4 t = *(const f16x4*)&Tb[(size_t)c * N + q * 4];
    const float sc = bcS[c][0], sh = bcS[c][1];
    float4 h;
    h.x = fmaxf((float)t[0] * sc + sh, 0.f);
    h.y = fmaxf((float)t[1] * sc + sh, 0.f);
    h.z = fmaxf((float)t[2] * sc + sh, 0.f);
    h.w = fmaxf((float)t[3] * sc + sh, 0.f);
    const size_t gi = (size_t)(b * C + c) * N + n0 + q * 4;
    if constexpr (RES) {
      const float4 ho = *(const float4*)&H[gi];
      h.x += ho.x; h.y += ho.y; h.z += ho.z; h.w += ho.w;
      *(float4*)&H[gi] = h;
      *(float4*)&OutS[(size_t)b * (4 * C * N) + (size_t)c * N + n0 + q * 4] = h;
    } else {
      *(float4*)&H[gi] = h;
    }
    XT[(q * 4 + 0) * 136 + c] = (_Float16)h.x;
    XT[(q * 4 + 1) * 136 + c] = (_Float16)h.y;
    XT[(q * 4 + 2) * 136 + c] = (_Float16)h.z;
    XT[(q * 4 + 3) * 136 + c] = (_Float16)h.w;
  }
  __syncthreads();
  const int w = tid >> 6, lane = tid & 63, quad = lane >> 4, lr = lane & 15;
  const int nt = w & 1, og = w >> 1;
  const int n = n0 + nt * 16 + lr;
  const int vld = mask[b * N + n] != 0;
  const int jc = psum[b * N + n];
  f32x4 acc[5];
  const _Float16* Aptr[5];
  int otl[5];
#pragma unroll
  for (int j = 0; j < 5; j++) {
    acc[j] = (f32x4){0.f, 0.f, 0.f, 0.f};
    const int ot = og + 2 * j;
    otl[j] = ot;
    Aptr[j] = (ot < 8) ? (WFv + (size_t)(ot * 16 + lr) * 128)
                       : (WFqk + (size_t)((ot - 8) * 16 + lr) * 128);
  }
#pragma unroll
  for (int kc = 0; kc < 4; kc++) {
    const f16x8 bf = *(const f16x8*)&XT[(nt * 16 + lr) * 136 + kc * 32 + quad * 8];
#pragma unroll
    for (int j = 0; j < 5; j++) {
      const f16x8 a = *(const f16x8*)&Aptr[j][kc * 32 + quad * 8];
      acc[j] = __builtin_amdgcn_mfma_f32_16x16x32_f16(a, bf, acc[j], 0, 0, 0);
    }
  }
#pragma unroll
  for (int j = 0; j < 5; j++) {
    const int ot = otl[j];
    if (ot < 8) {
      float v[4];
#pragma unroll
      for (int r = 0; r < 4; r++) v[r] = acc[j][r] + bv[ot * 16 + quad * 4 + r];
      if (vld) {
#pragma unroll
        for (int r = 0; r < 4; r++)
          XVc[(size_t)(b * C + ot * 16 + quad * 4 + r) * N + jc] = (_Float16)v[r];
      }
      float s[4];
#pragma unroll
      for (int r = 0; r < 4; r++) s[r] = vld ? 0.f : v[r];
#pragma unroll
      for (int o = 1; o <= 8; o <<= 1) {
#pragma unroll
        for (int r = 0; r < 4; r++) s[r] += __shfl_xor(s[r], o, 64);
      }
      if (lr == 0) {
#pragma unroll
        for (int r = 0; r < 4; r++) SP[nt][ot * 16 + quad * 4 + r] = s[r];
      }
    } else {
      f16x4 qv;
#pragma unroll
      for (int r = 0; r < 4; r++) qv[r] = (_Float16)acc[j][r];
      const int qo = (ot - 8) * 16 + quad * 4;
      *(f16x4*)&QT[((size_t)b * N + n) * 32 + qo] = qv;
      if (vld) *(f16x4*)&QTc[((size_t)b * N + jc) * 32 + qo] = qv;
    }
  }
  __syncthreads();
  if (tid < 128)
    xvp[(size_t)(b * C + tid) * 128 + blockIdx.x] = SP[0][tid] + SP[1][tid];
}

// ---------------------------------------------------------------------------
// Row stats over COMPACTED space, single-pass online softmax.
// 16 rows/block, pad-bias arithmetic (mrow<Nv).  Block bx==256 instead
// reduces xvp -> xvi.  rowst[b*N+row] = (rowmax, 1/rowsum).
// grid (257, B), block 512.
// ---------------------------------------------------------------------------
__global__ __launch_bounds__(512) void k_sm(const _Float16* __restrict__ QTc,
                                            const int* __restrict__ nvb,
                                            const float* __restrict__ xvp,
                                            float* __restrict__ xvi,
                                            float2* __restrict__ rowst) {
  const int b = blockIdx.y, tid = threadIdx.x;
  if (blockIdx.x == 256) {                   // xvi reduction block
    __shared__ float xr[128][4];
    const int c = tid >> 2, q = tid & 3;
    const float* src = xvp + (size_t)(b * C + c) * 128 + q * 32;
    float v = 0.f;
#pragma unroll
    for (int i = 0; i < 32; i++) v += src[i];
    xr[c][q] = v;
    __syncthreads();
    if (tid < 128) xvi[b * C + tid] = xr[tid][0] + xr[tid][1] + xr[tid][2] + xr[tid][3];
    return;
  }
  const int Nv = nvb[b];
  const int NvpB = (Nv + 63) & ~63;
  const int n0 = blockIdx.x * 16;
  if (n0 >= NvpB) return;
  __shared__ float redM[8][16], redS[8][16];
  const _Float16* Qb = QTc + (size_t)b * N * 32;
  const int w = tid >> 6, lane = tid & 63, quad = lane >> 4, lr = lane & 15;
  const f16x8 aF = *(const f16x8*)&Qb[(size_t)(n0 + lr) * 32 + quad * 8];
  float mx[4] = {-3e38f, -3e38f, -3e38f, -3e38f};
  float s[4] = {0.f, 0.f, 0.f, 0.f};
  for (int ms = 0; ms < NvpB; ms += 128) {   // 8 waves x 16 m-cols per iter
    const int mrow = ms + w * 16 + lr;
    const f16x8 bF = *(const f16x8*)&Qb[(size_t)mrow * 32 + quad * 8];
    f32x4 d = (f32x4){0.f, 0.f, 0.f, 0.f};
    d = __builtin_amdgcn_mfma_f32_16x16x32_f16(aF, bF, d, 0, 0, 0);
    const float bias = (mrow < Nv) ? 0.0f : -1e30f;
#pragma unroll
    for (int r = 0; r < 4; r++) {
      const float dv = d[r] + bias;
      if (dv > mx[r]) {                      // rare after warm-up (defer-max)
        s[r] *= __expf(mx[r] - dv);
        mx[r] = dv;
      }
      s[r] += __expf(dv - mx[r]);
    }
  }
  // merge (mx,s) across the 16 lr lanes (butterfly log-sum-exp)
#pragma unroll
  for (int r = 0; r < 4; r++) {
#pragma unroll
    for (int o = 1; o <= 8; o <<= 1) {
      const float mo = __shfl_xor(mx[r], o, 64);
      const float so = __shfl_xor(s[r], o, 64);
      const float mn = fmaxf(mx[r], mo);
      s[r] = s[r] * __expf(mx[r] - mn) + so * __expf(mo - mn);
      mx[r] = mn;
    }
  }
  if (lr == 0)
#pragma unroll
    for (int r = 0; r < 4; r++) {
      redM[w][quad * 4 + r] = mx[r];
      redS[w][quad * 4 + r] = s[r];
    }
  __syncthreads();
  if (tid < 16) {
    float M = redM[0][tid];
#pragma unroll
    for (int k = 1; k < 8; k++) M = fmaxf(M, redM[k][tid]);
    float tot = 0.f;
#pragma unroll
    for (int k = 0; k < 8; k++) tot += redS[k][tid] * __expf(redM[k][tid] - M);
    const int row = n0 + tid;
    const bool valid = row < Nv;
    float2 rv;
    rv.x = valid ? M : 1e30f;
    rv.y = valid ? (1.0f / tot) : 0.0f;
    rowst[b * N + row] = rv;
  }
}

// ---------------------------------------------------------------------------
// Fused Gram->exp->PV + wt-GEMM (R10-proven structure).  Stats via sharded
// atomics into st_out (replaces bnpart).
//   td = H - (acc + xvInvSum/4096) / (1e-9 + colS + ninv/4096)
// grid (N/32, B), block 512.
// ---------------------------------------------------------------------------
__global__ __launch_bounds__(512, 4) void k_pv(const _Float16* __restrict__ QT,
                                               const _Float16* __restrict__ QTc,
                                               const _Float16* __restrict__ XVc,
                                               const _Float16* __restrict__ WFt,
                                               const float* __restrict__ H,
                                               const int* __restrict__ mask,
                                               const float2* __restrict__ rowst,
                                               const int* __restrict__ nvb,
                                               const float* __restrict__ xvi,
                                               const float* __restrict__ bt,
                                               _Float16* __restrict__ T2h,
                                               float* __restrict__ st_out) {
  __shared__ _Float16 XVs[2][128 * 72];
  __shared__ _Float16 PsT[2][32 * 72];
  __shared__ float colPart[4][32];
  __shared__ float colS[32];
  const int tid = threadIdx.x;
  const int m0 = blockIdx.x * 32, b = blockIdx.y;
  const int Nv = nvb[b];
  const int ns = ((Nv + 63) & ~63) >> 6;
  const _Float16* Qa = QT + (size_t)b * N * 32;
  const _Float16* Qc = QTc + (size_t)b * N * 32;
  const _Float16* XVb = XVc + (size_t)(b * C) * N;
  const float2* rsB = rowst + (size_t)b * N;
  const int w = tid >> 6, lane = tid & 63, quad = lane >> 4, lr = lane & 15;
  const int msub = w & 1, nsub = w >> 1;
  // block-constant B-operand: Q at this block's m rows (original space)
  const f16x8 bGm = *(const f16x8*)&Qa[(size_t)(m0 + msub * 16 + lr) * 32 + quad * 8];
  const float vmb =
      (mask[b * N + m0 + msub * 16 + lr] != 0) ? 0.0f : -1e30f;  // per-thread m=lr
  const int sc0 = tid >> 3, sh0 = tid & 7;   // XV staging rows (2 vec/thread)
  const int sc1 = sc0 + 64;
  f32x4 acc[2];
  acc[0] = (f32x4){0.f, 0.f, 0.f, 0.f};
  acc[1] = (f32x4){0.f, 0.f, 0.f, 0.f};
  float cs = 0.f;                            // column-sum for m = lr (this msub)

  auto produce = [&](int k0, int bf) {
    // A-operand: Q at compacted n rows (varies per step)
    const f16x8 aGn = *(const f16x8*)&Qc[(size_t)(k0 + nsub * 16 + lr) * 32 + quad * 8];
    const f16x8 xv0 = *(const f16x8*)&XVb[(size_t)sc0 * N + k0 + sh0 * 8];
    const f16x8 xv1 = *(const f16x8*)&XVb[(size_t)sc1 * N + k0 + sh0 * 8];
    const int nb = k0 + nsub * 16 + quad * 4;          // this thread's 4 n values
    const float4 r01 = *(const float4*)&rsB[nb];       // (max0,ri0,max1,ri1)
    const float4 r23 = *(const float4*)&rsB[nb + 2];   // (max2,ri2,max3,ri3)
    f32x4 e = (f32x4){0.f, 0.f, 0.f, 0.f};
    e = __builtin_amdgcn_mfma_f32_16x16x32_f16(aGn, bGm, e, 0, 0, 0);
    *(f16x8*)&XVs[bf][sc0 * 72 + sh0 * 8] = xv0;
    *(f16x8*)&XVs[bf][sc1 * 72 + sh0 * 8] = xv1;
    const float p0 = __expf(e[0] - r01.x + vmb) * r01.y;  // pad rows: ri=0 -> 0
    const float p1 = __expf(e[1] - r01.z + vmb) * r01.w;
    const float p2 = __expf(e[2] - r23.x + vmb) * r23.y;
    const float p3 = __expf(e[3] - r23.z + vmb) * r23.w;
    cs += (p0 + p1) + (p2 + p3);
    f16x4 pp = {(_Float16)p0, (_Float16)p1, (_Float16)p2, (_Float16)p3};
    *(f16x4*)&PsT[bf][(msub * 16 + lr) * 72 + nsub * 16 + quad * 4] = pp;
  };
  auto consume = [&](int bf) {
    const int c0 = w * 16;
    const f16x8 a0 = *(const f16x8*)&XVs[bf][(c0 + lr) * 72 + quad * 8];
    const f16x8 a1 = *(const f16x8*)&XVs[bf][(c0 + lr) * 72 + 32 + quad * 8];
    const f16x8 b00 = *(const f16x8*)&PsT[bf][lr * 72 + quad * 8];
    const f16x8 b01 = *(const f16x8*)&PsT[bf][lr * 72 + 32 + quad * 8];
    const f16x8 b10 = *(const f16x8*)&PsT[bf][(16 + lr) * 72 + quad * 8];
    const f16x8 b11 = *(const f16x8*)&PsT[bf][(16 + lr) * 72 + 32 + quad * 8];
    acc[0] = __builtin_amdgcn_mfma_f32_16x16x32_f16(a0, b00, acc[0], 0, 0, 0);
    acc[0] = __builtin_amdgcn_mfma_f32_16x16x32_f16(a1, b01, acc[0], 0, 0, 0);
    acc[1] = __builtin_amdgcn_mfma_f32_16x16x32_f16(a0, b10, acc[1], 0, 0, 0);
    acc[1] = __builtin_amdgcn_mfma_f32_16x16x32_f16(a1, b11, acc[1], 0, 0, 0);
  };

  if (ns > 0) produce(0, 0);
  __syncthreads();
  for (int it = 0; it < ns; it += 2) {
    if (it + 1 < ns) produce((it + 1) * 64, 1);
    consume(0);
    __syncthreads();
    if (it + 1 < ns) {
      if (it + 2 < ns) produce((it + 2) * 64, 0);
      consume(1);
      __syncthreads();
    }
  }
  // reduce cs across the 4 quads (n-quarters of column m=lr)
  cs += __shfl_xor(cs, 16, 64);
  cs += __shfl_xor(cs, 32, 64);
  if (quad == 0) colPart[nsub][msub * 16 + lr] = cs;
  __syncthreads();
  if (tid < 32)
    colS[tid] = colPart[0][tid] + colPart[1][tid] + colPart[2][tid] + colPart[3][tid];
  __syncthreads();
  const float ninvq = (float)(N - Nv) * 0.000244140625f;   // ninv/4096
  const float rdiv0 = 1.0f / (1e-9f + colS[lr] + ninvq);
  const float rdiv1 = 1.0f / (1e-9f + colS[16 + lr] + ninvq);
  const int cg = w * 16 + quad * 4;          // local channel base
  // ---- td tile -> LDS (reuse XVs[0]; PV loop is done) ----
  _Float16* TdS = &XVs[0][0];                // [32 m][136 c]
  {
    f16x4 t0, t1;
#pragma unroll
    for (int r = 0; r < 4; r++) {
      const float xadd = xvi[b * C + cg + r] * 0.000244140625f;  // xvInvSum/4096
      const size_t gi0 = (size_t)(b * C + cg + r) * N + m0 + lr;
      const size_t gi1 = gi0 + 16;
      t0[r] = (_Float16)(H[gi0] - (acc[0][r] + xadd) * rdiv0);
      t1[r] = (_Float16)(H[gi1] - (acc[1][r] + xadd) * rdiv1);
    }
    *(f16x4*)&TdS[lr * 136 + cg] = t0;
    *(f16x4*)&TdS[(16 + lr) * 136 + cg] = t1;
  }
  __syncthreads();
  // ---- fused wt-GEMM: out[o, m0..m0+31] = wt·td + bt; wave w owns o-tile w
  f32x4 acc2[2];
  acc2[0] = (f32x4){0.f, 0.f, 0.f, 0.f};
  acc2[1] = (f32x4){0.f, 0.f, 0.f, 0.f};
#pragma unroll
  for (int kc = 0; kc < 4; kc++) {
    const f16x8 aT = *(const f16x8*)&WFt[(size_t)(w * 16 + lr) * 128 + kc * 32 + quad * 8];
    const f16x8 bT0 = *(const f16x8*)&TdS[lr * 136 + kc * 32 + quad * 8];
    const f16x8 bT1 = *(const f16x8*)&TdS[(16 + lr) * 136 + kc * 32 + quad * 8];
    acc2[0] = __builtin_amdgcn_mfma_f32_16x16x32_f16(aT, bT0, acc2[0], 0, 0, 0);
    acc2[1] = __builtin_amdgcn_mfma_f32_16x16x32_f16(aT, bT1, acc2[1], 0, 0, 0);
  }
  const int oo = w * 16 + quad * 4;
  float* shd = st_out + (blockIdx.x & 3) * 256;
#pragma unroll
  for (int r = 0; r < 4; r++) {
    const float v0 = acc2[0][r] + bt[oo + r];
    const float v1 = acc2[1][r] + bt[oo + r];
    const size_t go = (size_t)(b * C + oo + r) * N + m0 + lr;
    T2h[go] = (_Float16)v0;
    T2h[go + 16] = (_Float16)v1;
    float s = v0 + v1, q = v0 * v0 + v1 * v1;
    s += __shfl_xor(s, 1, 64); q += __shfl_xor(q, 1, 64);
    s += __shfl_xor(s, 2, 64); q += __shfl_xor(q, 2, 64);
    s += __shfl_xor(s, 4, 64); q += __shfl_xor(q, 4, 64);
    s += __shfl_xor(s, 8, 64); q += __shfl_xor(q, 8, 64);
    if (lr == 0) {
      atomicAdd(&shd[oo + r], s);
      atomicAdd(&shd[128 + oo + r], q);
    }
  }
}

// ---------------------------------------------------------------------------
// Final apply (layer 3): Out = relu(bn(T2)) + H.  Coefficients read directly
// from sharded stats (no partial reduction); H not rewritten (dead).
// grid 2048, 256 thr.
// ---------------------------------------------------------------------------
__global__ __launch_bounds__(256) void k_applyF(const _Float16* __restrict__ T2,
                                                const float* __restrict__ st,
                                                const float* __restrict__ gamma,
                                                const float* __restrict__ beta,
                                                const float* __restrict__ H,
                                                float* __restrict__ Out) {
  const int tid = threadIdx.x;
  const int f = (blockIdx.x * 256 + tid) * 4;
  const int c = (blockIdx.x >> 2) & 127;
  const float2 bc = bn_coef(st, c, gamma, beta);
  const f16x4 t = *(const f16x4*)&T2[f];
  const float4 h = *(const float4*)&H[f];
  float4 r;
  r.x = fmaxf((float)t[0] * bc.x + bc.y, 0.f) + h.x;
  r.y = fmaxf((float)t[1] * bc.x + bc.y, 0.f) + h.y;
  r.z = fmaxf((float)t[2] * bc.x + bc.y, 0.f) + h.z;
  r.w = fmaxf((float)t[3] * bc.x + bc.y, 0.f) + h.w;
  const int b = f >> 19;                // f / (C*N)
  const int rem = f & (C * N - 1);      // c*N + n
  *(float4*)&Out[(size_t)b * (4 * C * N) + rem] = r;
}

// ---------------------------------------------------------------------------
extern "C" void kernel_launch(void* const* d_in, const int* in_sizes, int n_in,
                              void* d_out, int out_size, void* d_ws, size_t ws_size,
                              hipStream_t stream) {
  const float* x    = (const float*)d_in[0];
  const int*   mask = (const int*)  d_in[1];
  const float* w1   = (const float*)d_in[2];
  const float* g1   = (const float*)d_in[3];
  const float* b1   = (const float*)d_in[4];
  const float* w2   = (const float*)d_in[5];
  const float* g2   = (const float*)d_in[6];
  const float* b2   = (const float*)d_in[7];
  const float* wqk  = (const float*)d_in[8];
  const float* wv   = (const float*)d_in[9];
  const float* bv   = (const float*)d_in[10];
  const float* wt   = (const float*)d_in[11];
  const float* bt   = (const float*)d_in[12];
  const float* sg   = (const float*)d_in[13];
  const float* sb   = (const float*)d_in[14];
  float* out = (float*)d_out;

  char* p = (char*)d_ws;
  auto alloc = [&](size_t bytes) { char* r = p; p += (bytes + 255) & ~(size_t)255; return r; };
  float*    H      = (float*)   alloc((size_t)B * C * N * 4);
  _Float16* T2a    = (_Float16*)alloc((size_t)B * C * N * 2);
  _Float16* T2b    = (_Float16*)alloc((size_t)B * C * N * 2);
  _Float16* QT     = (_Float16*)alloc((size_t)B * N * 32 * 2);
  _Float16* QTc    = (_Float16*)alloc((size_t)B * N * 32 * 2);   // contiguous with
  _Float16* XVc    = (_Float16*)alloc((size_t)B * C * N * 2);    // XVc + bnstat:
  float*    bnstat = (float*)   alloc((size_t)6 * 1024 * 4);     // one memset
  float2*   rowst  = (float2*)  alloc((size_t)B * N * 8);
  int*      psum   = (int*)     alloc((size_t)B * N * 4);
  int*      nvb    = (int*)     alloc(256);
  float*    xvp    = (float*)   alloc((size_t)B * C * 128 * 4);
  float*    xvi    = (float*)   alloc((size_t)B * C * 4);
  _Float16* WF     = (_Float16*)alloc((size_t)180224 * 2);
  (void)ws_size;
  _Float16* wf1  = WF;
  _Float16* wf2  = WF + 16384;
  _Float16* wfv  = WF + 32768;
  _Float16* wft  = WF + 98304;
  _Float16* wfqk = WF + 163840;
  auto st = [&](int k) { return bnstat + (size_t)k * 1024; };

  // ---- one-shot setup: weight convert, mask compaction, pad+stat zeroing ----
  k_wcvt<<<176, 256, 0, stream>>>(w1, w2, wv, wt, wqk, WF);
  k_mask<<<B, 1024, 0, stream>>>(mask, psum, nvb);
  hipMemsetAsync(QTc, 0,
                 (size_t)B * N * 32 * 2 + (size_t)B * C * N * 2 + (size_t)6 * 1024 * 4,
                 stream);

  // ---- stem: gwm1 -> (BN1 fused into) gwm2 ----
  k_gwm<false><<<dim3(64, 2, B), 512, 0, stream>>>(wf1, x, nullptr, nullptr, nullptr,
                                                   T2a, st(0));
  k_gwm<true><<<dim3(64, 2, B), 512, 0, stream>>>(wf2, T2a, st(0), g1, b1, T2b, st(1));

  // ---- 4 chained offset-attention layers ----
  for (int L = 0; L < 4; L++) {
    if (L == 0)
      k_qvF<false><<<dim3(128, B), 256, 0, stream>>>(
          wfv, wfqk, T2b, st(1), g2, b2, H, nullptr, bv, mask, psum, XVc, QT, QTc, xvp);
    else
      k_qvF<true><<<dim3(128, B), 256, 0, stream>>>(
          wfv + (size_t)L * 16384, wfqk + (size_t)L * 4096, T2a, st(1 + L),
          sg + (L - 1) * C, sb + (L - 1) * C, H, out + (size_t)(L - 1) * C * N,
          bv + L * C, mask, psum, XVc, QT, QTc, xvp);
    k_sm<<<dim3(257, B), 512, 0, stream>>>(QTc, nvb, xvp, xvi, rowst);
    k_pv<<<dim3(128, B), 512, 0, stream>>>(QT, QTc, XVc, wft + (size_t)L * 16384, H, mask,
                                           rowst, nvb, xvi, bt + L * C, T2a, st(2 + L));
  }
  k_applyF<<<2048, 256, 0, stream>>>(T2a, st(5), sg + 3 * C, sb + 3 * C, H,
                                     out + (size_t)3 * C * N);
}

// Round 14
// 388.873 us; speedup vs baseline: 1.0762x; 1.0762x over previous
//
#include <hip/hip_runtime.h>
#include <hip/hip_fp16.h>

constexpr int C = 128;
constexpr int N = 4096;
constexpr int B = 4;
constexpr int SH = 16;     // stat shards per site (atomic-contention control)

typedef _Float16 f16x8 __attribute__((ext_vector_type(8)));
typedef _Float16 f16x4 __attribute__((ext_vector_type(4)));
typedef float    f32x4 __attribute__((ext_vector_type(4)));

// bnstat site layout: st[shard<SH][256]: [c]=sum, [128+c]=sumsq.
__device__ __forceinline__ float2 bn_coef(const float* __restrict__ st, int c,
                                          const float* __restrict__ gamma,
                                          const float* __restrict__ beta) {
  float s = 0.f, q = 0.f;
#pragma unroll
  for (int k = 0; k < SH; k++) {
    s += st[k * 256 + c];
    q += st[k * 256 + 128 + c];
  }
  const float inv = 1.0f / (B * N);
  const float mean = s * inv;
  const float var = q * inv - mean * mean;    // biased, like torch BN
  const float sc = gamma[c] * rsqrtf(var + 1e-5f);
  return {sc, beta[c] - mean * sc};
}

// ---------------------------------------------------------------------------
// One-shot weight convert fp32 -> f16 into workspace, concatenated:
// [w1(16K) | w2(16K) | wv(64K) | wt(64K) | wqk(16K)] elements.
// grid 176, 256 thr; each thread converts one float4.
// ---------------------------------------------------------------------------
__global__ __launch_bounds__(256) void k_wcvt(const float* __restrict__ w1,
                                              const float* __restrict__ w2,
                                              const float* __restrict__ wv,
                                              const float* __restrict__ wt,
                                              const float* __restrict__ wqk,
                                              _Float16* __restrict__ WF) {
  const int g = blockIdx.x * 256 + threadIdx.x;   // float4 index
  const float* src; int off;
  if (g < 4096)       { src = w1;  off = g; }
  else if (g < 8192)  { src = w2;  off = g - 4096; }
  else if (g < 24576) { src = wv;  off = g - 8192; }
  else if (g < 40960) { src = wt;  off = g - 24576; }
  else                { src = wqk; off = g - 40960; }
  const float4 v = ((const float4*)src)[off];
  f16x4 h = {(_Float16)v.x, (_Float16)v.y, (_Float16)v.z, (_Float16)v.w};
  *(f16x4*)&WF[(size_t)g * 4] = h;
}

// ---------------------------------------------------------------------------
// Mask compaction: exclusive prefix sum of (mask!=0) per batch + valid count.
// grid B, 1024 thr (4 elements/thread).
// ---------------------------------------------------------------------------
__global__ __launch_bounds__(1024) void k_mask(const int* __restrict__ mask,
                                               int* __restrict__ psum,
                                               int* __restrict__ nvb) {
  const int b = blockIdx.x, tid = threadIdx.x;
  __shared__ int wsum[16];
  const int4 mv = *(const int4*)&mask[b * N + tid * 4];
  const int m0 = (mv.x != 0), m1 = (mv.y != 0), m2 = (mv.z != 0), m3 = (mv.w != 0);
  const int s0 = m0, s1 = s0 + m1, s2 = s1 + m2, s3 = s2 + m3;
  const int lane = tid & 63, w = tid >> 6;
  int sc = s3;
#pragma unroll
  for (int o = 1; o < 64; o <<= 1) {
    const int v = __shfl_up(sc, o, 64);
    if (lane >= o) sc += v;
  }
  if (lane == 63) wsum[w] = sc;
  __syncthreads();
  if (tid < 16) {
    int v = wsum[tid];
#pragma unroll
    for (int o = 1; o < 16; o <<= 1) {
      const int u = __shfl_up(v, o, 64);
      if (tid >= o) v += u;
    }
    wsum[tid] = v;
  }
  __syncthreads();
  const int excl = ((w > 0) ? wsum[w - 1] : 0) + sc - s3;
  int4 pv;
  pv.x = excl; pv.y = excl + s0; pv.z = excl + s1; pv.w = excl + s2;
  *(int4*)&psum[b * N + tid * 4] = pv;
  if (tid == 0) nvb[b] = wsum[15];
}

// ---------------------------------------------------------------------------
// Stem GEMM, optionally fused with the PREVIOUS stage's BN+ReLU (FUSE_BN:
// input is f16 pre-BN T2; coefficients from st_in; stem1 activation never
// touches HBM).  Y f16 out; stats -> SH-sharded atomics in st_out.
// grid (N/64, 2, B), block 512.
// ---------------------------------------------------------------------------
template<bool FUSE_BN>
__global__ __launch_bounds__(512) void k_gwm(const _Float16* __restrict__ WF,
                                             const void* __restrict__ Xv,
                                             const float* __restrict__ st_in,
                                             const float* __restrict__ gamma,
                                             const float* __restrict__ beta,
                                             _Float16* __restrict__ Y,
                                             float* __restrict__ st_out) {
  __shared__ _Float16 XT[64 * 136];          // [n][c], stride 136 (16B-aligned rows)
  __shared__ float statP[4][64], statQ[4][64];
  __shared__ float bcS[128][2];
  const int tid = threadIdx.x;
  const int n0 = blockIdx.x * 64, oh = blockIdx.y, b = blockIdx.z;
  if constexpr (FUSE_BN) {
    if (tid < 128) {
      const float2 bc = bn_coef(st_in, tid, gamma, beta);
      bcS[tid][0] = bc.x; bcS[tid][1] = bc.y;
    }
    __syncthreads();
    const _Float16* Xb = (const _Float16*)Xv + (size_t)(b * C) * N + n0;
#pragma unroll
    for (int i = 0; i < 4; i++) {            // 2048 f16x4: c=idx>>4, q=idx&15
      const int idx = tid + i * 512;
      const int c = idx >> 4, q = idx & 15;
      const f16x4 t = *(const f16x4*)&Xb[(size_t)c * N + q * 4];
      const float sc = bcS[c][0], sh = bcS[c][1];
#pragma unroll
      for (int e = 0; e < 4; e++)
        XT[(q * 4 + e) * 136 + c] = (_Float16)fmaxf((float)t[e] * sc + sh, 0.f);
    }
  } else {
    const float* Xb = (const float*)Xv + (size_t)(b * C) * N + n0;
#pragma unroll
    for (int i = 0; i < 4; i++) {            // 2048 float4: c=idx>>4, q=idx&15
      const int idx = tid + i * 512;
      const int c = idx >> 4, q = idx & 15;
      const float4 v = *(const float4*)&Xb[(size_t)c * N + q * 4];
      XT[(q * 4 + 0) * 136 + c] = (_Float16)v.x;
      XT[(q * 4 + 1) * 136 + c] = (_Float16)v.y;
      XT[(q * 4 + 2) * 136 + c] = (_Float16)v.z;
      XT[(q * 4 + 3) * 136 + c] = (_Float16)v.w;
    }
  }
  __syncthreads();
  const int w = tid >> 6, lane = tid & 63, quad = lane >> 4, lr = lane & 15;
  const int nt = w & 3, og = w >> 2;
  const int ob[2] = {oh * 64 + og * 16, oh * 64 + (og + 2) * 16};
  f16x8 aW[2][4];
#pragma unroll
  for (int t = 0; t < 2; t++)
#pragma unroll
    for (int kc = 0; kc < 4; kc++)
      aW[t][kc] = *(const f16x8*)&WF[(size_t)(ob[t] + lr) * 128 + kc * 32 + quad * 8];
  f32x4 acc[2];
  acc[0] = (f32x4){0.f, 0.f, 0.f, 0.f};
  acc[1] = (f32x4){0.f, 0.f, 0.f, 0.f};
#pragma unroll
  for (int kc = 0; kc < 4; kc++) {
    const f16x8 bf = *(const f16x8*)&XT[(nt * 16 + lr) * 136 + kc * 32 + quad * 8];
    acc[0] = __builtin_amdgcn_mfma_f32_16x16x32_f16(aW[0][kc], bf, acc[0], 0, 0, 0);
    acc[1] = __builtin_amdgcn_mfma_f32_16x16x32_f16(aW[1][kc], bf, acc[1], 0, 0, 0);
  }
#pragma unroll
  for (int t = 0; t < 2; t++) {
#pragma unroll
    for (int r = 0; r < 4; r++) {
      const int o = ob[t] + quad * 4 + r;
      const float val = acc[t][r];
      Y[(size_t)(b * C + o) * N + n0 + nt * 16 + lr] = (_Float16)val;
      float s = val, q = val * val;
      s += __shfl_xor(s, 1, 64); q += __shfl_xor(q, 1, 64);
      s += __shfl_xor(s, 2, 64); q += __shfl_xor(q, 2, 64);
      s += __shfl_xor(s, 4, 64); q += __shfl_xor(q, 4, 64);
      s += __shfl_xor(s, 8, 64); q += __shfl_xor(q, 8, 64);
      if (lr == 0) { statP[nt][o - oh * 64] = s; statQ[nt][o - oh * 64] = q; }
    }
  }
  __syncthreads();
  if (tid < 64) {
    const int o = oh * 64 + tid;
    const float s = statP[0][tid] + statP[1][tid] + statP[2][tid] + statP[3][tid];
    const float q = statQ[0][tid] + statQ[1][tid] + statQ[2][tid] + statQ[3][tid];
    float* sh = st_out + (blockIdx.x & (SH - 1)) * 256;
    atomicAdd(&sh[o], s);
    atomicAdd(&sh[128 + o], q);
  }
}

// ---------------------------------------------------------------------------
// Fused [prev-layer BN+ReLU(+residual)+Out] + XV/QT projection.
// Staging computes h = relu(bn(T2)) (+H_old), writes H (+Out slice), then
// projects h.  Outputs: QT/QTc/XVc/xvp as before.
// grid (N/32, B), block 256.
// ---------------------------------------------------------------------------
template<bool RES>
__global__ __launch_bounds__(256) void k_qvF(const _Float16* __restrict__ WFv,
                                             const _Float16* __restrict__ WFqk,
                                             const _Float16* __restrict__ T2,
                                             const float* __restrict__ st_in,
                                             const float* __restrict__ gamma,
                                             const float* __restrict__ beta,
                                             float* __restrict__ H,
                                             float* __restrict__ OutS,
                                             const float* __restrict__ bv,
                                             const int* __restrict__ mask,
                                             const int* __restrict__ psum,
                                             _Float16* __restrict__ XVc,
                                             _Float16* __restrict__ QT,
                                             _Float16* __restrict__ QTc,
                                             float* __restrict__ xvp) {
  __shared__ _Float16 XT[32 * 136];
  __shared__ float SP[2][128];
  __shared__ float bcS[128][2];
  const int tid = threadIdx.x;
  const int n0 = blockIdx.x * 32, b = blockIdx.y;
  if (tid < 128) {
    const float2 bc = bn_coef(st_in, tid, gamma, beta);
    bcS[tid][0] = bc.x; bcS[tid][1] = bc.y;
  }
  __syncthreads();
  const _Float16* Tb = T2 + (size_t)(b * C) * N + n0;
#pragma unroll
  for (int i = 0; i < 4; i++) {              // 1024 quads: c=idx>>3, q=idx&7
    const int idx = tid + i * 256;
    const int c = idx >> 3, q = idx & 7;
    const f16x4 t = *(const f16x4*)&Tb[(size_t)c * N + q * 4];
    const float sc = bcS[c][0], sh = bcS[c][1];
    float4 h;
    h.x = fmaxf((float)t[0] * sc + sh, 0.f);
    h.y = fmaxf((float)t[1] * sc + sh, 0.f);
    h.z = fmaxf((float)t[2] * sc + sh, 0.f);
    h.w = fmaxf((float)t[3] * sc + sh, 0.f);
    const size_t gi = (size_t)(b * C + c) * N + n0 + q * 4;
    if constexpr (RES) {
      const float4 ho = *(const float4*)&H[gi];
      h.x += ho.x; h.y += ho.y; h.z += ho.z; h.w += ho.w;
      *(float4*)&H[gi] = h;
      *(float4*)&OutS[(size_t)b * (4 * C * N) + (size_t)c * N + n0 + q * 4] = h;
    } else {
      *(float4*)&H[gi] = h;
    }
    XT[(q * 4 + 0) * 136 + c] = (_Float16)h.x;
    XT[(q * 4 + 1) * 136 + c] = (_Float16)h.y;
    XT[(q * 4 + 2) * 136 + c] = (_Float16)h.z;
    XT[(q * 4 + 3) * 136 + c] = (_Float16)h.w;
  }
  __syncthreads();
  const int w = tid >> 6, lane = tid & 63, quad = lane >> 4, lr = lane & 15;
  const int nt = w & 1, og = w >> 1;
  const int n = n0 + nt * 16 + lr;
  const int vld = mask[b * N + n] != 0;
  const int jc = psum[b * N + n];
  f32x4 acc[5];
  const _Float16* Aptr[5];
  int otl[5];
#pragma unroll
  for (int j = 0; j < 5; j++) {
    acc[j] = (f32x4){0.f, 0.f, 0.f, 0.f};
    const int ot = og + 2 * j;
    otl[j] = ot;
    Aptr[j] = (ot < 8) ? (WFv + (size_t)(ot * 16 + lr) * 128)
                       : (WFqk + (size_t)((ot - 8) * 16 + lr) * 128);
  }
#pragma unroll
  for (int kc = 0; kc < 4; kc++) {
    const f16x8 bf = *(const f16x8*)&XT[(nt * 16 + lr) * 136 + kc * 32 + quad * 8];
#pragma unroll
    for (int j = 0; j < 5; j++) {
      const f16x8 a = *(const f16x8*)&Aptr[j][kc * 32 + quad * 8];
      acc[j] = __builtin_amdgcn_mfma_f32_16x16x32_f16(a, bf, acc[j], 0, 0, 0);
    }
  }
#pragma unroll
  for (int j = 0; j < 5; j++) {
    const int ot = otl[j];
    if (ot < 8) {
      float v[4];
#pragma unroll
      for (int r = 0; r < 4; r++) v[r] = acc[j][r] + bv[ot * 16 + quad * 4 + r];
      if (vld) {
#pragma unroll
        for (int r = 0; r < 4; r++)
          XVc[(size_t)(b * C + ot * 16 + quad * 4 + r) * N + jc] = (_Float16)v[r];
      }
      float s[4];
#pragma unroll
      for (int r = 0; r < 4; r++) s[r] = vld ? 0.f : v[r];
#pragma unroll
      for (int o = 1; o <= 8; o <<= 1) {
#pragma unroll
        for (int r = 0; r < 4; r++) s[r] += __shfl_xor(s[r], o, 64);
      }
      if (lr == 0) {
#pragma unroll
        for (int r = 0; r < 4; r++) SP[nt][ot * 16 + quad * 4 + r] = s[r];
      }
    } else {
      f16x4 qv;
#pragma unroll
      for (int r = 0; r < 4; r++) qv[r] = (_Float16)acc[j][r];
      const int qo = (ot - 8) * 16 + quad * 4;
      *(f16x4*)&QT[((size_t)b * N + n) * 32 + qo] = qv;
      if (vld) *(f16x4*)&QTc[((size_t)b * N + jc) * 32 + qo] = qv;
    }
  }
  __syncthreads();
  if (tid < 128)
    xvp[(size_t)(b * C + tid) * 128 + blockIdx.x] = SP[0][tid] + SP[1][tid];
}

// ---------------------------------------------------------------------------
// Row stats over COMPACTED space, single-pass online softmax.
// 16 rows/block, pad-bias arithmetic (mrow<Nv).  Block bx==256 instead
// reduces xvp -> xvi.  rowst[b*N+row] = (rowmax, 1/rowsum).
// grid (257, B), block 512.
// ---------------------------------------------------------------------------
__global__ __launch_bounds__(512) void k_sm(const _Float16* __restrict__ QTc,
                                            const int* __restrict__ nvb,
                                            const float* __restrict__ xvp,
                                            float* __restrict__ xvi,
                                            float2* __restrict__ rowst) {
  const int b = blockIdx.y, tid = threadIdx.x;
  if (blockIdx.x == 256) {                   // xvi reduction block
    __shared__ float xr[128][4];
    const int c = tid >> 2, q = tid & 3;
    const float* src = xvp + (size_t)(b * C + c) * 128 + q * 32;
    float v = 0.f;
#pragma unroll
    for (int i = 0; i < 32; i++) v += src[i];
    xr[c][q] = v;
    __syncthreads();
    if (tid < 128) xvi[b * C + tid] = xr[tid][0] + xr[tid][1] + xr[tid][2] + xr[tid][3];
    return;
  }
  const int Nv = nvb[b];
  const int NvpB = (Nv + 63) & ~63;
  const int n0 = blockIdx.x * 16;
  if (n0 >= NvpB) return;
  __shared__ float redM[8][16], redS[8][16];
  const _Float16* Qb = QTc + (size_t)b * N * 32;
  const int w = tid >> 6, lane = tid & 63, quad = lane >> 4, lr = lane & 15;
  const f16x8 aF = *(const f16x8*)&Qb[(size_t)(n0 + lr) * 32 + quad * 8];
  float mx[4] = {-3e38f, -3e38f, -3e38f, -3e38f};
  float s[4] = {0.f, 0.f, 0.f, 0.f};
  for (int ms = 0; ms < NvpB; ms += 128) {   // 8 waves x 16 m-cols per iter
    const int mrow = ms + w * 16 + lr;
    const f16x8 bF = *(const f16x8*)&Qb[(size_t)mrow * 32 + quad * 8];
    f32x4 d = (f32x4){0.f, 0.f, 0.f, 0.f};
    d = __builtin_amdgcn_mfma_f32_16x16x32_f16(aF, bF, d, 0, 0, 0);
    const float bias = (mrow < Nv) ? 0.0f : -1e30f;
#pragma unroll
    for (int r = 0; r < 4; r++) {
      const float dv = d[r] + bias;
      if (dv > mx[r]) {                      // rare after warm-up (defer-max)
        s[r] *= __expf(mx[r] - dv);
        mx[r] = dv;
      }
      s[r] += __expf(dv - mx[r]);
    }
  }
  // merge (mx,s) across the 16 lr lanes (butterfly log-sum-exp)
#pragma unroll
  for (int r = 0; r < 4; r++) {
#pragma unroll
    for (int o = 1; o <= 8; o <<= 1) {
      const float mo = __shfl_xor(mx[r], o, 64);
      const float so = __shfl_xor(s[r], o, 64);
      const float mn = fmaxf(mx[r], mo);
      s[r] = s[r] * __expf(mx[r] - mn) + so * __expf(mo - mn);
      mx[r] = mn;
    }
  }
  if (lr == 0)
#pragma unroll
    for (int r = 0; r < 4; r++) {
      redM[w][quad * 4 + r] = mx[r];
      redS[w][quad * 4 + r] = s[r];
    }
  __syncthreads();
  if (tid < 16) {
    float M = redM[0][tid];
#pragma unroll
    for (int k = 1; k < 8; k++) M = fmaxf(M, redM[k][tid]);
    float tot = 0.f;
#pragma unroll
    for (int k = 0; k < 8; k++) tot += redS[k][tid] * __expf(redM[k][tid] - M);
    const int row = n0 + tid;
    const bool valid = row < Nv;
    float2 rv;
    rv.x = valid ? M : 1e30f;
    rv.y = valid ? (1.0f / tot) : 0.0f;
    rowst[b * N + row] = rv;
  }
}

// ---------------------------------------------------------------------------
// Fused Gram->exp->PV + wt-GEMM (R10-proven structure).  Stats via SH-sharded
// atomics into st_out.
//   td = H - (acc + xvInvSum/4096) / (1e-9 + colS + ninv/4096)
// grid (N/32, B), block 512.
// ---------------------------------------------------------------------------
__global__ __launch_bounds__(512, 4) void k_pv(const _Float16* __restrict__ QT,
                                               const _Float16* __restrict__ QTc,
                                               const _Float16* __restrict__ XVc,
                                               const _Float16* __restrict__ WFt,
                                               const float* __restrict__ H,
                                               const int* __restrict__ mask,
                                               const float2* __restrict__ rowst,
                                               const int* __restrict__ nvb,
                                               const float* __restrict__ xvi,
                                               const float* __restrict__ bt,
                                               _Float16* __restrict__ T2h,
                                               float* __restrict__ st_out) {
  __shared__ _Float16 XVs[2][128 * 72];
  __shared__ _Float16 PsT[2][32 * 72];
  __shared__ float colPart[4][32];
  __shared__ float colS[32];
  const int tid = threadIdx.x;
  const int m0 = blockIdx.x * 32, b = blockIdx.y;
  const int Nv = nvb[b];
  const int ns = ((Nv + 63) & ~63) >> 6;
  const _Float16* Qa = QT + (size_t)b * N * 32;
  const _Float16* Qc = QTc + (size_t)b * N * 32;
  const _Float16* XVb = XVc + (size_t)(b * C) * N;
  const float2* rsB = rowst + (size_t)b * N;
  const int w = tid >> 6, lane = tid & 63, quad = lane >> 4, lr = lane & 15;
  const int msub = w & 1, nsub = w >> 1;
  // block-constant B-operand: Q at this block's m rows (original space)
  const f16x8 bGm = *(const f16x8*)&Qa[(size_t)(m0 + msub * 16 + lr) * 32 + quad * 8];
  const float vmb =
      (mask[b * N + m0 + msub * 16 + lr] != 0) ? 0.0f : -1e30f;  // per-thread m=lr
  const int sc0 = tid >> 3, sh0 = tid & 7;   // XV staging rows (2 vec/thread)
  const int sc1 = sc0 + 64;
  f32x4 acc[2];
  acc[0] = (f32x4){0.f, 0.f, 0.f, 0.f};
  acc[1] = (f32x4){0.f, 0.f, 0.f, 0.f};
  float cs = 0.f;                            // column-sum for m = lr (this msub)

  auto produce = [&](int k0, int bf) {
    // A-operand: Q at compacted n rows (varies per step)
    const f16x8 aGn = *(const f16x8*)&Qc[(size_t)(k0 + nsub * 16 + lr) * 32 + quad * 8];
    const f16x8 xv0 = *(const f16x8*)&XVb[(size_t)sc0 * N + k0 + sh0 * 8];
    const f16x8 xv1 = *(const f16x8*)&XVb[(size_t)sc1 * N + k0 + sh0 * 8];
    const int nb = k0 + nsub * 16 + quad * 4;          // this thread's 4 n values
    const float4 r01 = *(const float4*)&rsB[nb];       // (max0,ri0,max1,ri1)
    const float4 r23 = *(const float4*)&rsB[nb + 2];   // (max2,ri2,max3,ri3)
    f32x4 e = (f32x4){0.f, 0.f, 0.f, 0.f};
    e = __builtin_amdgcn_mfma_f32_16x16x32_f16(aGn, bGm, e, 0, 0, 0);
    *(f16x8*)&XVs[bf][sc0 * 72 + sh0 * 8] = xv0;
    *(f16x8*)&XVs[bf][sc1 * 72 + sh0 * 8] = xv1;
    const float p0 = __expf(e[0] - r01.x + vmb) * r01.y;  // pad rows: ri=0 -> 0
    const float p1 = __expf(e[1] - r01.z + vmb) * r01.w;
    const float p2 = __expf(e[2] - r23.x + vmb) * r23.y;
    const float p3 = __expf(e[3] - r23.z + vmb) * r23.w;
    cs += (p0 + p1) + (p2 + p3);
    f16x4 pp = {(_Float16)p0, (_Float16)p1, (_Float16)p2, (_Float16)p3};
    *(f16x4*)&PsT[bf][(msub * 16 + lr) * 72 + nsub * 16 + quad * 4] = pp;
  };
  auto consume = [&](int bf) {
    const int c0 = w * 16;
    const f16x8 a0 = *(const f16x8*)&XVs[bf][(c0 + lr) * 72 + quad * 8];
    const f16x8 a1 = *(const f16x8*)&XVs[bf][(c0 + lr) * 72 + 32 + quad * 8];
    const f16x8 b00 = *(const f16x8*)&PsT[bf][lr * 72 + quad * 8];
    const f16x8 b01 = *(const f16x8*)&PsT[bf][lr * 72 + 32 + quad * 8];
    const f16x8 b10 = *(const f16x8*)&PsT[bf][(16 + lr) * 72 + quad * 8];
    const f16x8 b11 = *(const f16x8*)&PsT[bf][(16 + lr) * 72 + 32 + quad * 8];
    acc[0] = __builtin_amdgcn_mfma_f32_16x16x32_f16(a0, b00, acc[0], 0, 0, 0);
    acc[0] = __builtin_amdgcn_mfma_f32_16x16x32_f16(a1, b01, acc[0], 0, 0, 0);
    acc[1] = __builtin_amdgcn_mfma_f32_16x16x32_f16(a0, b10, acc[1], 0, 0, 0);
    acc[1] = __builtin_amdgcn_mfma_f32_16x16x32_f16(a1, b11, acc[1], 0, 0, 0);
  };

  if (ns > 0) produce(0, 0);
  __syncthreads();
  for (int it = 0; it < ns; it += 2) {
    if (it + 1 < ns) produce((it + 1) * 64, 1);
    consume(0);
    __syncthreads();
    if (it + 1 < ns) {
      if (it + 2 < ns) produce((it + 2) * 64, 0);
      consume(1);
      __syncthreads();
    }
  }
  // reduce cs across the 4 quads (n-quarters of column m=lr)
  cs += __shfl_xor(cs, 16, 64);
  cs += __shfl_xor(cs, 32, 64);
  if (quad == 0) colPart[nsub][msub * 16 + lr] = cs;
  __syncthreads();
  if (tid < 32)
    colS[tid] = colPart[0][tid] + colPart[1][tid] + colPart[2][tid] + colPart[3][tid];
  __syncthreads();
  const float ninvq = (float)(N - Nv) * 0.000244140625f;   // ninv/4096
  const float rdiv0 = 1.0f / (1e-9f + colS[lr] + ninvq);
  const float rdiv1 = 1.0f / (1e-9f + colS[16 + lr] + ninvq);
  const int cg = w * 16 + quad * 4;          // local channel base
  // ---- td tile -> LDS (reuse XVs[0]; PV loop is done) ----
  _Float16* TdS = &XVs[0][0];                // [32 m][136 c]
  {
    f16x4 t0, t1;
#pragma unroll
    for (int r = 0; r < 4; r++) {
      const float xadd = xvi[b * C + cg + r] * 0.000244140625f;  // xvInvSum/4096
      const size_t gi0 = (size_t)(b * C + cg + r) * N + m0 + lr;
      const size_t gi1 = gi0 + 16;
      t0[r] = (_Float16)(H[gi0] - (acc[0][r] + xadd) * rdiv0);
      t1[r] = (_Float16)(H[gi1] - (acc[1][r] + xadd) * rdiv1);
    }
    *(f16x4*)&TdS[lr * 136 + cg] = t0;
    *(f16x4*)&TdS[(16 + lr) * 136 + cg] = t1;
  }
  __syncthreads();
  // ---- fused wt-GEMM: out[o, m0..m0+31] = wt·td + bt; wave w owns o-tile w
  f32x4 acc2[2];
  acc2[0] = (f32x4){0.f, 0.f, 0.f, 0.f};
  acc2[1] = (f32x4){0.f, 0.f, 0.f, 0.f};
#pragma unroll
  for (int kc = 0; kc < 4; kc++) {
    const f16x8 aT = *(const f16x8*)&WFt[(size_t)(w * 16 + lr) * 128 + kc * 32 + quad * 8];
    const f16x8 bT0 = *(const f16x8*)&TdS[lr * 136 + kc * 32 + quad * 8];
    const f16x8 bT1 = *(const f16x8*)&TdS[(16 + lr) * 136 + kc * 32 + quad * 8];
    acc2[0] = __builtin_amdgcn_mfma_f32_16x16x32_f16(aT, bT0, acc2[0], 0, 0, 0);
    acc2[1] = __builtin_amdgcn_mfma_f32_16x16x32_f16(aT, bT1, acc2[1], 0, 0, 0);
  }
  const int oo = w * 16 + quad * 4;
  float* shd = st_out + (blockIdx.x & (SH - 1)) * 256;
#pragma unroll
  for (int r = 0; r < 4; r++) {
    const float v0 = acc2[0][r] + bt[oo + r];
    const float v1 = acc2[1][r] + bt[oo + r];
    const size_t go = (size_t)(b * C + oo + r) * N + m0 + lr;
    T2h[go] = (_Float16)v0;
    T2h[go + 16] = (_Float16)v1;
    float s = v0 + v1, q = v0 * v0 + v1 * v1;
    s += __shfl_xor(s, 1, 64); q += __shfl_xor(q, 1, 64);
    s += __shfl_xor(s, 2, 64); q += __shfl_xor(q, 2, 64);
    s += __shfl_xor(s, 4, 64); q += __shfl_xor(q, 4, 64);
    s += __shfl_xor(s, 8, 64); q += __shfl_xor(q, 8, 64);
    if (lr == 0) {
      atomicAdd(&shd[oo + r], s);
      atomicAdd(&shd[128 + oo + r], q);
    }
  }
}

// ---------------------------------------------------------------------------
// Final apply (layer 3): Out = relu(bn(T2)) + H.  Coefficients read directly
// from sharded stats; H not rewritten (dead).
// grid 2048, 256 thr.
// ---------------------------------------------------------------------------
__global__ __launch_bounds__(256) void k_applyF(const _Float16* __restrict__ T2,
                                                const float* __restrict__ st,
                                                const float* __restrict__ gamma,
                                                const float* __restrict__ beta,
                                                const float* __restrict__ H,
                                                float* __restrict__ Out) {
  const int tid = threadIdx.x;
  const int f = (blockIdx.x * 256 + tid) * 4;
  const int c = (blockIdx.x >> 2) & 127;
  const float2 bc = bn_coef(st, c, gamma, beta);
  const f16x4 t = *(const f16x4*)&T2[f];
  const float4 h = *(const float4*)&H[f];
  float4 r;
  r.x = fmaxf((float)t[0] * bc.x + bc.y, 0.f) + h.x;
  r.y = fmaxf((float)t[1] * bc.x + bc.y, 0.f) + h.y;
  r.z = fmaxf((float)t[2] * bc.x + bc.y, 0.f) + h.z;
  r.w = fmaxf((float)t[3] * bc.x + bc.y, 0.f) + h.w;
  const int b = f >> 19;                // f / (C*N)
  const int rem = f & (C * N - 1);      // c*N + n
  *(float4*)&Out[(size_t)b * (4 * C * N) + rem] = r;
}

// ---------------------------------------------------------------------------
extern "C" void kernel_launch(void* const* d_in, const int* in_sizes, int n_in,
                              void* d_out, int out_size, void* d_ws, size_t ws_size,
                              hipStream_t stream) {
  const float* x    = (const float*)d_in[0];
  const int*   mask = (const int*)  d_in[1];
  const float* w1   = (const float*)d_in[2];
  const float* g1   = (const float*)d_in[3];
  const float* b1   = (const float*)d_in[4];
  const float* w2   = (const float*)d_in[5];
  const float* g2   = (const float*)d_in[6];
  const float* b2   = (const float*)d_in[7];
  const float* wqk  = (const float*)d_in[8];
  const float* wv   = (const float*)d_in[9];
  const float* bv   = (const float*)d_in[10];
  const float* wt   = (const float*)d_in[11];
  const float* bt   = (const float*)d_in[12];
  const float* sg   = (const float*)d_in[13];
  const float* sb   = (const float*)d_in[14];
  float* out = (float*)d_out;

  char* p = (char*)d_ws;
  auto alloc = [&](size_t bytes) { char* r = p; p += (bytes + 255) & ~(size_t)255; return r; };
  float*    H      = (float*)   alloc((size_t)B * C * N * 4);
  _Float16* T2a    = (_Float16*)alloc((size_t)B * C * N * 2);
  _Float16* T2b    = (_Float16*)alloc((size_t)B * C * N * 2);
  _Float16* QT     = (_Float16*)alloc((size_t)B * N * 32 * 2);
  _Float16* QTc    = (_Float16*)alloc((size_t)B * N * 32 * 2);   // contiguous with
  _Float16* XVc    = (_Float16*)alloc((size_t)B * C * N * 2);    // XVc + bnstat:
  float*    bnstat = (float*)   alloc((size_t)6 * SH * 256 * 4); // one memset
  float2*   rowst  = (float2*)  alloc((size_t)B * N * 8);
  int*      psum   = (int*)     alloc((size_t)B * N * 4);
  int*      nvb    = (int*)     alloc(256);
  float*    xvp    = (float*)   alloc((size_t)B * C * 128 * 4);
  float*    xvi    = (float*)   alloc((size_t)B * C * 4);
  _Float16* WF     = (_Float16*)alloc((size_t)180224 * 2);
  (void)ws_size;
  _Float16* wf1  = WF;
  _Float16* wf2  = WF + 16384;
  _Float16* wfv  = WF + 32768;
  _Float16* wft  = WF + 98304;
  _Float16* wfqk = WF + 163840;
  auto st = [&](int k) { return bnstat + (size_t)k * SH * 256; };

  // ---- one-shot setup: weight convert, mask compaction, pad+stat zeroing ----
  k_wcvt<<<176, 256, 0, stream>>>(w1, w2, wv, wt, wqk, WF);
  k_mask<<<B, 1024, 0, stream>>>(mask, psum, nvb);
  hipMemsetAsync(QTc, 0,
                 (size_t)B * N * 32 * 2 + (size_t)B * C * N * 2 +
                 (size_t)6 * SH * 256 * 4,
                 stream);

  // ---- stem: gwm1 -> (BN1 fused into) gwm2 ----
  k_gwm<false><<<dim3(64, 2, B), 512, 0, stream>>>(wf1, x, nullptr, nullptr, nullptr,
                                                   T2a, st(0));
  k_gwm<true><<<dim3(64, 2, B), 512, 0, stream>>>(wf2, T2a, st(0), g1, b1, T2b, st(1));

  // ---- 4 chained offset-attention layers ----
  for (int L = 0; L < 4; L++) {
    if (L == 0)
      k_qvF<false><<<dim3(128, B), 256, 0, stream>>>(
          wfv, wfqk, T2b, st(1), g2, b2, H, nullptr, bv, mask, psum, XVc, QT, QTc, xvp);
    else
      k_qvF<true><<<dim3(128, B), 256, 0, stream>>>(
          wfv + (size_t)L * 16384, wfqk + (size_t)L * 4096, T2a, st(1 + L),
          sg + (L - 1) * C, sb + (L - 1) * C, H, out + (size_t)(L - 1) * C * N,
          bv + L * C, mask, psum, XVc, QT, QTc, xvp);
    k_sm<<<dim3(257, B), 512, 0, stream>>>(QTc, nvb, xvp, xvi, rowst);
    k_pv<<<dim3(128, B), 512, 0, stream>>>(QT, QTc, XVc, wft + (size_t)L * 16384, H, mask,
                                           rowst, nvb, xvi, bt + L * C, T2a, st(2 + L));
  }
  k_applyF<<<2048, 256, 0, stream>>>(T2a, st(5), sg + 3 * C, sb + 3 * C, H,
                                     out + (size_t)3 * C * N);
}

// Round 16
// 386.495 us; speedup vs baseline: 1.0828x; 1.0062x over previous
//
#include <hip/hip_runtime.h>
#include <hip/hip_fp16.h>

constexpr int C = 128;
constexpr int N = 4096;
constexpr int B = 4;
constexpr int SH = 16;     // stat shards per site (atomic-contention control)

typedef _Float16 f16x8 __attribute__((ext_vector_type(8)));
typedef _Float16 f16x4 __attribute__((ext_vector_type(4)));
typedef float    f32x4 __attribute__((ext_vector_type(4)));

// bnstat site layout: st[shard<SH][256]: [c]=sum, [128+c]=sumsq.
__device__ __forceinline__ float2 bn_coef(const float* __restrict__ st, int c,
                                          const float* __restrict__ gamma,
                                          const float* __restrict__ beta) {
  float s = 0.f, q = 0.f;
#pragma unroll
  for (int k = 0; k < SH; k++) {
    s += st[k * 256 + c];
    q += st[k * 256 + 128 + c];
  }
  const float inv = 1.0f / (B * N);
  const float mean = s * inv;
  const float var = q * inv - mean * mean;    // biased, like torch BN
  const float sc = gamma[c] * rsqrtf(var + 1e-5f);
  return {sc, beta[c] - mean * sc};
}

// ---------------------------------------------------------------------------
// One-shot weight convert fp32 -> f16 into workspace, concatenated:
// [w1(16K) | w2(16K) | wv(64K) | wt(64K) | wqk(16K)] elements.
// grid 176, 256 thr; each thread converts one float4.
// ---------------------------------------------------------------------------
__global__ __launch_bounds__(256) void k_wcvt(const float* __restrict__ w1,
                                              const float* __restrict__ w2,
                                              const float* __restrict__ wv,
                                              const float* __restrict__ wt,
                                              const float* __restrict__ wqk,
                                              _Float16* __restrict__ WF) {
  const int g = blockIdx.x * 256 + threadIdx.x;   // float4 index
  const float* src; int off;
  if (g < 4096)       { src = w1;  off = g; }
  else if (g < 8192)  { src = w2;  off = g - 4096; }
  else if (g < 24576) { src = wv;  off = g - 8192; }
  else if (g < 40960) { src = wt;  off = g - 24576; }
  else                { src = wqk; off = g - 40960; }
  const float4 v = ((const float4*)src)[off];
  f16x4 h = {(_Float16)v.x, (_Float16)v.y, (_Float16)v.z, (_Float16)v.w};
  *(f16x4*)&WF[(size_t)g * 4] = h;
}

// ---------------------------------------------------------------------------
// Mask compaction: exclusive prefix sum of (mask!=0) per batch + valid count.
// grid B, 1024 thr (4 elements/thread).
// ---------------------------------------------------------------------------
__global__ __launch_bounds__(1024) void k_mask(const int* __restrict__ mask,
                                               int* __restrict__ psum,
                                               int* __restrict__ nvb) {
  const int b = blockIdx.x, tid = threadIdx.x;
  __shared__ int wsum[16];
  const int4 mv = *(const int4*)&mask[b * N + tid * 4];
  const int m0 = (mv.x != 0), m1 = (mv.y != 0), m2 = (mv.z != 0), m3 = (mv.w != 0);
  const int s0 = m0, s1 = s0 + m1, s2 = s1 + m2, s3 = s2 + m3;
  const int lane = tid & 63, w = tid >> 6;
  int sc = s3;
#pragma unroll
  for (int o = 1; o < 64; o <<= 1) {
    const int v = __shfl_up(sc, o, 64);
    if (lane >= o) sc += v;
  }
  if (lane == 63) wsum[w] = sc;
  __syncthreads();
  if (tid < 16) {
    int v = wsum[tid];
#pragma unroll
    for (int o = 1; o < 16; o <<= 1) {
      const int u = __shfl_up(v, o, 64);
      if (tid >= o) v += u;
    }
    wsum[tid] = v;
  }
  __syncthreads();
  const int excl = ((w > 0) ? wsum[w - 1] : 0) + sc - s3;
  int4 pv;
  pv.x = excl; pv.y = excl + s0; pv.z = excl + s1; pv.w = excl + s2;
  *(int4*)&psum[b * N + tid * 4] = pv;
  if (tid == 0) nvb[b] = wsum[15];
}

// ---------------------------------------------------------------------------
// Stem GEMM, optionally fused with the PREVIOUS stage's BN+ReLU (FUSE_BN:
// input is f16 pre-BN T2; coefficients from st_in; stem1 activation never
// touches HBM).  Y f16 out; stats -> SH-sharded atomics in st_out.
// grid (N/64, 2, B), block 512.
// ---------------------------------------------------------------------------
template<bool FUSE_BN>
__global__ __launch_bounds__(512) void k_gwm(const _Float16* __restrict__ WF,
                                             const void* __restrict__ Xv,
                                             const float* __restrict__ st_in,
                                             const float* __restrict__ gamma,
                                             const float* __restrict__ beta,
                                             _Float16* __restrict__ Y,
                                             float* __restrict__ st_out) {
  __shared__ _Float16 XT[64 * 136];          // [n][c], stride 136 (16B-aligned rows)
  __shared__ float statP[4][64], statQ[4][64];
  __shared__ float bcS[128][2];
  const int tid = threadIdx.x;
  const int n0 = blockIdx.x * 64, oh = blockIdx.y, b = blockIdx.z;
  if constexpr (FUSE_BN) {
    if (tid < 128) {
      const float2 bc = bn_coef(st_in, tid, gamma, beta);
      bcS[tid][0] = bc.x; bcS[tid][1] = bc.y;
    }
    __syncthreads();
    const _Float16* Xb = (const _Float16*)Xv + (size_t)(b * C) * N + n0;
#pragma unroll
    for (int i = 0; i < 4; i++) {            // 2048 f16x4: c=idx>>4, q=idx&15
      const int idx = tid + i * 512;
      const int c = idx >> 4, q = idx & 15;
      const f16x4 t = *(const f16x4*)&Xb[(size_t)c * N + q * 4];
      const float sc = bcS[c][0], sh = bcS[c][1];
#pragma unroll
      for (int e = 0; e < 4; e++)
        XT[(q * 4 + e) * 136 + c] = (_Float16)fmaxf((float)t[e] * sc + sh, 0.f);
    }
  } else {
    const float* Xb = (const float*)Xv + (size_t)(b * C) * N + n0;
#pragma unroll
    for (int i = 0; i < 4; i++) {            // 2048 float4: c=idx>>4, q=idx&15
      const int idx = tid + i * 512;
      const int c = idx >> 4, q = idx & 15;
      const float4 v = *(const float4*)&Xb[(size_t)c * N + q * 4];
      XT[(q * 4 + 0) * 136 + c] = (_Float16)v.x;
      XT[(q * 4 + 1) * 136 + c] = (_Float16)v.y;
      XT[(q * 4 + 2) * 136 + c] = (_Float16)v.z;
      XT[(q * 4 + 3) * 136 + c] = (_Float16)v.w;
    }
  }
  __syncthreads();
  const int w = tid >> 6, lane = tid & 63, quad = lane >> 4, lr = lane & 15;
  const int nt = w & 3, og = w >> 2;
  const int ob[2] = {oh * 64 + og * 16, oh * 64 + (og + 2) * 16};
  f16x8 aW[2][4];
#pragma unroll
  for (int t = 0; t < 2; t++)
#pragma unroll
    for (int kc = 0; kc < 4; kc++)
      aW[t][kc] = *(const f16x8*)&WF[(size_t)(ob[t] + lr) * 128 + kc * 32 + quad * 8];
  f32x4 acc[2];
  acc[0] = (f32x4){0.f, 0.f, 0.f, 0.f};
  acc[1] = (f32x4){0.f, 0.f, 0.f, 0.f};
#pragma unroll
  for (int kc = 0; kc < 4; kc++) {
    const f16x8 bf = *(const f16x8*)&XT[(nt * 16 + lr) * 136 + kc * 32 + quad * 8];
    acc[0] = __builtin_amdgcn_mfma_f32_16x16x32_f16(aW[0][kc], bf, acc[0], 0, 0, 0);
    acc[1] = __builtin_amdgcn_mfma_f32_16x16x32_f16(aW[1][kc], bf, acc[1], 0, 0, 0);
  }
#pragma unroll
  for (int t = 0; t < 2; t++) {
#pragma unroll
    for (int r = 0; r < 4; r++) {
      const int o = ob[t] + quad * 4 + r;
      const float val = acc[t][r];
      Y[(size_t)(b * C + o) * N + n0 + nt * 16 + lr] = (_Float16)val;
      float s = val, q = val * val;
      s += __shfl_xor(s, 1, 64); q += __shfl_xor(q, 1, 64);
      s += __shfl_xor(s, 2, 64); q += __shfl_xor(q, 2, 64);
      s += __shfl_xor(s, 4, 64); q += __shfl_xor(q, 4, 64);
      s += __shfl_xor(s, 8, 64); q += __shfl_xor(q, 8, 64);
      if (lr == 0) { statP[nt][o - oh * 64] = s; statQ[nt][o - oh * 64] = q; }
    }
  }
  __syncthreads();
  if (tid < 64) {
    const int o = oh * 64 + tid;
    const float s = statP[0][tid] + statP[1][tid] + statP[2][tid] + statP[3][tid];
    const float q = statQ[0][tid] + statQ[1][tid] + statQ[2][tid] + statQ[3][tid];
    float* sh = st_out + (blockIdx.x & (SH - 1)) * 256;
    atomicAdd(&sh[o], s);
    atomicAdd(&sh[128 + o], q);
  }
}

// ---------------------------------------------------------------------------
// Fused [prev-layer BN+ReLU(+residual)+Out] + XV/QT projection.
// QT buffer dropped -- only QTc is written (k_pv reads original-space m
// rows via psum indirection).
// grid (N/32, B), block 256.
// ---------------------------------------------------------------------------
template<bool RES>
__global__ __launch_bounds__(256) void k_qvF(const _Float16* __restrict__ WFv,
                                             const _Float16* __restrict__ WFqk,
                                             const _Float16* __restrict__ T2,
                                             const float* __restrict__ st_in,
                                             const float* __restrict__ gamma,
                                             const float* __restrict__ beta,
                                             float* __restrict__ H,
                                             float* __restrict__ OutS,
                                             const float* __restrict__ bv,
                                             const int* __restrict__ mask,
                                             const int* __restrict__ psum,
                                             _Float16* __restrict__ XVc,
                                             _Float16* __restrict__ QTc,
                                             float* __restrict__ xvp) {
  __shared__ _Float16 XT[32 * 136];
  __shared__ float SP[2][128];
  __shared__ float bcS[128][2];
  const int tid = threadIdx.x;
  const int n0 = blockIdx.x * 32, b = blockIdx.y;
  if (tid < 128) {
    const float2 bc = bn_coef(st_in, tid, gamma, beta);
    bcS[tid][0] = bc.x; bcS[tid][1] = bc.y;
  }
  __syncthreads();
  const _Float16* Tb = T2 + (size_t)(b * C) * N + n0;
#pragma unroll
  for (int i = 0; i < 4; i++) {              // 1024 quads: c=idx>>3, q=idx&7
    const int idx = tid + i * 256;
    const int c = idx >> 3, q = idx & 7;
    const f16x4 t = *(const f16x4*)&Tb[(size_t)c * N + q * 4];
    const float sc = bcS[c][0], sh = bcS[c][1];
    float4 h;
    h.x = fmaxf((float)t[0] * sc + sh, 0.f);
    h.y = fmaxf((float)t[1] * sc + sh, 0.f);
    h.z = fmaxf((float)t[2] * sc + sh, 0.f);
    h.w = fmaxf((float)t[3] * sc + sh, 0.f);
    const size_t gi = (size_t)(b * C + c) * N + n0 + q * 4;
    if constexpr (RES) {
      const float4 ho = *(const float4*)&H[gi];
      h.x += ho.x; h.y += ho.y; h.z += ho.z; h.w += ho.w;
      *(float4*)&H[gi] = h;
      *(float4*)&OutS[(size_t)b * (4 * C * N) + (size_t)c * N + n0 + q * 4] = h;
    } else {
      *(float4*)&H[gi] = h;
    }
    XT[(q * 4 + 0) * 136 + c] = (_Float16)h.x;
    XT[(q * 4 + 1) * 136 + c] = (_Float16)h.y;
    XT[(q * 4 + 2) * 136 + c] = (_Float16)h.z;
    XT[(q * 4 + 3) * 136 + c] = (_Float16)h.w;
  }
  __syncthreads();
  const int w = tid >> 6, lane = tid & 63, quad = lane >> 4, lr = lane & 15;
  const int nt = w & 1, og = w >> 1;
  const int n = n0 + nt * 16 + lr;
  const int vld = mask[b * N + n] != 0;
  const int jc = psum[b * N + n];
  f32x4 acc[5];
  const _Float16* Aptr[5];
  int otl[5];
#pragma unroll
  for (int j = 0; j < 5; j++) {
    acc[j] = (f32x4){0.f, 0.f, 0.f, 0.f};
    const int ot = og + 2 * j;
    otl[j] = ot;
    Aptr[j] = (ot < 8) ? (WFv + (size_t)(ot * 16 + lr) * 128)
                       : (WFqk + (size_t)((ot - 8) * 16 + lr) * 128);
  }
#pragma unroll
  for (int kc = 0; kc < 4; kc++) {
    const f16x8 bf = *(const f16x8*)&XT[(nt * 16 + lr) * 136 + kc * 32 + quad * 8];
#pragma unroll
    for (int j = 0; j < 5; j++) {
      const f16x8 a = *(const f16x8*)&Aptr[j][kc * 32 + quad * 8];
      acc[j] = __builtin_amdgcn_mfma_f32_16x16x32_f16(a, bf, acc[j], 0, 0, 0);
    }
  }
#pragma unroll
  for (int j = 0; j < 5; j++) {
    const int ot = otl[j];
    if (ot < 8) {
      float v[4];
#pragma unroll
      for (int r = 0; r < 4; r++) v[r] = acc[j][r] + bv[ot * 16 + quad * 4 + r];
      if (vld) {
#pragma unroll
        for (int r = 0; r < 4; r++)
          XVc[(size_t)(b * C + ot * 16 + quad * 4 + r) * N + jc] = (_Float16)v[r];
      }
      float s[4];
#pragma unroll
      for (int r = 0; r < 4; r++) s[r] = vld ? 0.f : v[r];
#pragma unroll
      for (int o = 1; o <= 8; o <<= 1) {
#pragma unroll
        for (int r = 0; r < 4; r++) s[r] += __shfl_xor(s[r], o, 64);
      }
      if (lr == 0) {
#pragma unroll
        for (int r = 0; r < 4; r++) SP[nt][ot * 16 + quad * 4 + r] = s[r];
      }
    } else {
      if (vld) {
        f16x4 qv;
#pragma unroll
        for (int r = 0; r < 4; r++) qv[r] = (_Float16)acc[j][r];
        const int qo = (ot - 8) * 16 + quad * 4;
        *(f16x4*)&QTc[((size_t)b * N + jc) * 32 + qo] = qv;
      }
    }
  }
  __syncthreads();
  if (tid < 128)
    xvp[(size_t)(b * C + tid) * 128 + blockIdx.x] = SP[0][tid] + SP[1][tid];
}

// ---------------------------------------------------------------------------
// Row stats over COMPACTED space, single-pass online softmax.
// 16 rows/block, pad-bias arithmetic (mrow<Nv).  Block bx==256 instead
// reduces xvp -> xvi.  rowst[b*N+row] = (rowmax, 1/rowsum).
// grid (257, B), block 512.
// ---------------------------------------------------------------------------
__global__ __launch_bounds__(512) void k_sm(const _Float16* __restrict__ QTc,
                                            const int* __restrict__ nvb,
                                            const float* __restrict__ xvp,
                                            float* __restrict__ xvi,
                                            float2* __restrict__ rowst) {
  const int b = blockIdx.y, tid = threadIdx.x;
  if (blockIdx.x == 256) {                   // xvi reduction block
    __shared__ float xr[128][4];
    const int c = tid >> 2, q = tid & 3;
    const float* src = xvp + (size_t)(b * C + c) * 128 + q * 32;
    float v = 0.f;
#pragma unroll
    for (int i = 0; i < 32; i++) v += src[i];
    xr[c][q] = v;
    __syncthreads();
    if (tid < 128) xvi[b * C + tid] = xr[tid][0] + xr[tid][1] + xr[tid][2] + xr[tid][3];
    return;
  }
  const int Nv = nvb[b];
  const int NvpB = (Nv + 63) & ~63;
  const int n0 = blockIdx.x * 16;
  if (n0 >= NvpB) return;
  __shared__ float redM[8][16], redS[8][16];
  const _Float16* Qb = QTc + (size_t)b * N * 32;
  const int w = tid >> 6, lane = tid & 63, quad = lane >> 4, lr = lane & 15;
  const f16x8 aF = *(const f16x8*)&Qb[(size_t)(n0 + lr) * 32 + quad * 8];
  float mx[4] = {-3e38f, -3e38f, -3e38f, -3e38f};
  float s[4] = {0.f, 0.f, 0.f, 0.f};
  for (int ms = 0; ms < NvpB; ms += 128) {   // 8 waves x 16 m-cols per iter
    const int mrow = ms + w * 16 + lr;
    const f16x8 bF = *(const f16x8*)&Qb[(size_t)mrow * 32 + quad * 8];
    f32x4 d = (f32x4){0.f, 0.f, 0.f, 0.f};
    d = __builtin_amdgcn_mfma_f32_16x16x32_f16(aF, bF, d, 0, 0, 0);
    const float bias = (mrow < Nv) ? 0.0f : -1e30f;
#pragma unroll
    for (int r = 0; r < 4; r++) {
      const float dv = d[r] + bias;
      if (dv > mx[r]) {                      // rare after warm-up (defer-max)
        s[r] *= __expf(mx[r] - dv);
        mx[r] = dv;
      }
      s[r] += __expf(dv - mx[r]);
    }
  }
  // merge (mx,s) across the 16 lr lanes (butterfly log-sum-exp)
#pragma unroll
  for (int r = 0; r < 4; r++) {
#pragma unroll
    for (int o = 1; o <= 8; o <<= 1) {
      const float mo = __shfl_xor(mx[r], o, 64);
      const float so = __shfl_xor(s[r], o, 64);
      const float mn = fmaxf(mx[r], mo);
      s[r] = s[r] * __expf(mx[r] - mn) + so * __expf(mo - mn);
      mx[r] = mn;
    }
  }
  if (lr == 0)
#pragma unroll
    for (int r = 0; r < 4; r++) {
      redM[w][quad * 4 + r] = mx[r];
      redS[w][quad * 4 + r] = s[r];
    }
  __syncthreads();
  if (tid < 16) {
    float M = redM[0][tid];
#pragma unroll
    for (int k = 1; k < 8; k++) M = fmaxf(M, redM[k][tid]);
    float tot = 0.f;
#pragma unroll
    for (int k = 0; k < 8; k++) tot += redS[k][tid] * __expf(redM[k][tid] - M);
    const int row = n0 + tid;
    const bool valid = row < Nv;
    float2 rv;
    rv.x = valid ? M : 1e30f;
    rv.y = valid ? (1.0f / tot) : 0.0f;
    rowst[b * N + row] = rv;
  }
}

// ---------------------------------------------------------------------------
// Fused Gram->exp->PV + wt-GEMM (R10-proven structure).  B-operand Q at
// original m via psum indirection into QTc (QT buffer deleted); invalid m
// reads a finite valid/pad row, masked by vmb.  Stats via SH-sharded atomics.
//   td = H - (acc + xvInvSum/4096) / (1e-9 + colS + ninv/4096)
// grid (N/32, B), block 512.
// ---------------------------------------------------------------------------
__global__ __launch_bounds__(512, 4) void k_pv(const _Float16* __restrict__ QTc,
                                               const _Float16* __restrict__ XVc,
                                               const _Float16* __restrict__ WFt,
                                               const float* __restrict__ H,
                                               const int* __restrict__ mask,
                                               const int* __restrict__ psum,
                                               const float2* __restrict__ rowst,
                                               const int* __restrict__ nvb,
                                               const float* __restrict__ xvi,
                                               const float* __restrict__ bt,
                                               _Float16* __restrict__ T2h,
                                               float* __restrict__ st_out) {
  __shared__ _Float16 XVs[2][128 * 72];
  __shared__ _Float16 PsT[2][32 * 72];
  __shared__ float colPart[4][32];
  __shared__ float colS[32];
  const int tid = threadIdx.x;
  const int m0 = blockIdx.x * 32, b = blockIdx.y;
  const int Nv = nvb[b];
  const int ns = ((Nv + 63) & ~63) >> 6;
  const _Float16* Qc = QTc + (size_t)b * N * 32;
  const _Float16* XVb = XVc + (size_t)(b * C) * N;
  const float2* rsB = rowst + (size_t)b * N;
  const int w = tid >> 6, lane = tid & 63, quad = lane >> 4, lr = lane & 15;
  const int msub = w & 1, nsub = w >> 1;
  // block-constant B-operand: Q at this block's m rows via psum indirection
  const int mrow = m0 + msub * 16 + lr;
  const int jm = psum[b * N + mrow];
  const f16x8 bGm = *(const f16x8*)&Qc[(size_t)jm * 32 + quad * 8];
  const float vmb = (mask[b * N + mrow] != 0) ? 0.0f : -1e30f;   // per-thread m=lr
  const int sc0 = tid >> 3, sh0 = tid & 7;   // XV staging rows (2 vec/thread)
  const int sc1 = sc0 + 64;
  f32x4 acc[2];
  acc[0] = (f32x4){0.f, 0.f, 0.f, 0.f};
  acc[1] = (f32x4){0.f, 0.f, 0.f, 0.f};
  float cs = 0.f;                            // column-sum for m = lr (this msub)

  auto produce = [&](int k0, int bf) {
    // A-operand: Q at compacted n rows (varies per step)
    const f16x8 aGn = *(const f16x8*)&Qc[(size_t)(k0 + nsub * 16 + lr) * 32 + quad * 8];
    const f16x8 xv0 = *(const f16x8*)&XVb[(size_t)sc0 * N + k0 + sh0 * 8];
    const f16x8 xv1 = *(const f16x8*)&XVb[(size_t)sc1 * N + k0 + sh0 * 8];
    const int nb = k0 + nsub * 16 + quad * 4;          // this thread's 4 n values
    const float4 r01 = *(const float4*)&rsB[nb];       // (max0,ri0,max1,ri1)
    const float4 r23 = *(const float4*)&rsB[nb + 2];   // (max2,ri2,max3,ri3)
    f32x4 e = (f32x4){0.f, 0.f, 0.f, 0.f};
    e = __builtin_amdgcn_mfma_f32_16x16x32_f16(aGn, bGm, e, 0, 0, 0);
    *(f16x8*)&XVs[bf][sc0 * 72 + sh0 * 8] = xv0;
    *(f16x8*)&XVs[bf][sc1 * 72 + sh0 * 8] = xv1;
    const float p0 = __expf(e[0] - r01.x + vmb) * r01.y;  // pad rows: ri=0 -> 0
    const float p1 = __expf(e[1] - r01.z + vmb) * r01.w;
    const float p2 = __expf(e[2] - r23.x + vmb) * r23.y;
    const float p3 = __expf(e[3] - r23.z + vmb) * r23.w;
    cs += (p0 + p1) + (p2 + p3);
    f16x4 pp = {(_Float16)p0, (_Float16)p1, (_Float16)p2, (_Float16)p3};
    *(f16x4*)&PsT[bf][(msub * 16 + lr) * 72 + nsub * 16 + quad * 4] = pp;
  };
  auto consume = [&](int bf) {
    const int c0 = w * 16;
    const f16x8 a0 = *(const f16x8*)&XVs[bf][(c0 + lr) * 72 + quad * 8];
    const f16x8 a1 = *(const f16x8*)&XVs[bf][(c0 + lr) * 72 + 32 + quad * 8];
    const f16x8 b00 = *(const f16x8*)&PsT[bf][lr * 72 + quad * 8];
    const f16x8 b01 = *(const f16x8*)&PsT[bf][lr * 72 + 32 + quad * 8];
    const f16x8 b10 = *(const f16x8*)&PsT[bf][(16 + lr) * 72 + quad * 8];
    const f16x8 b11 = *(const f16x8*)&PsT[bf][(16 + lr) * 72 + 32 + quad * 8];
    acc[0] = __builtin_amdgcn_mfma_f32_16x16x32_f16(a0, b00, acc[0], 0, 0, 0);
    acc[0] = __builtin_amdgcn_mfma_f32_16x16x32_f16(a1, b01, acc[0], 0, 0, 0);
    acc[1] = __builtin_amdgcn_mfma_f32_16x16x32_f16(a0, b10, acc[1], 0, 0, 0);
    acc[1] = __builtin_amdgcn_mfma_f32_16x16x32_f16(a1, b11, acc[1], 0, 0, 0);
  };

  if (ns > 0) produce(0, 0);
  __syncthreads();
  for (int it = 0; it < ns; it += 2) {
    if (it + 1 < ns) produce((it + 1) * 64, 1);
    consume(0);
    __syncthreads();
    if (it + 1 < ns) {
      if (it + 2 < ns) produce((it + 2) * 64, 0);
      consume(1);
      __syncthreads();
    }
  }
  // reduce cs across the 4 quads (n-quarters of column m=lr)
  cs += __shfl_xor(cs, 16, 64);
  cs += __shfl_xor(cs, 32, 64);
  if (quad == 0) colPart[nsub][msub * 16 + lr] = cs;
  __syncthreads();
  if (tid < 32)
    colS[tid] = colPart[0][tid] + colPart[1][tid] + colPart[2][tid] + colPart[3][tid];
  __syncthreads();
  const float ninvq = (float)(N - Nv) * 0.000244140625f;   // ninv/4096
  const float rdiv0 = 1.0f / (1e-9f + colS[lr] + ninvq);
  const float rdiv1 = 1.0f / (1e-9f + colS[16 + lr] + ninvq);
  const int cg = w * 16 + quad * 4;          // local channel base
  // ---- td tile -> LDS (reuse XVs[0]; PV loop is done) ----
  _Float16* TdS = &XVs[0][0];                // [32 m][136 c]
  {
    f16x4 t0, t1;
#pragma unroll
    for (int r = 0; r < 4; r++) {
      const float xadd = xvi[b * C + cg + r] * 0.000244140625f;  // xvInvSum/4096
      const size_t gi0 = (size_t)(b * C + cg + r) * N + m0 + lr;
      const size_t gi1 = gi0 + 16;
      t0[r] = (_Float16)(H[gi0] - (acc[0][r] + xadd) * rdiv0);
      t1[r] = (_Float16)(H[gi1] - (acc[1][r] + xadd) * rdiv1);
    }
    *(f16x4*)&TdS[lr * 136 + cg] = t0;
    *(f16x4*)&TdS[(16 + lr) * 136 + cg] = t1;
  }
  __syncthreads();
  // ---- fused wt-GEMM: out[o, m0..m0+31] = wt·td + bt; wave w owns o-tile w
  f32x4 acc2[2];
  acc2[0] = (f32x4){0.f, 0.f, 0.f, 0.f};
  acc2[1] = (f32x4){0.f, 0.f, 0.f, 0.f};
#pragma unroll
  for (int kc = 0; kc < 4; kc++) {
    const f16x8 aT = *(const f16x8*)&WFt[(size_t)(w * 16 + lr) * 128 + kc * 32 + quad * 8];
    const f16x8 bT0 = *(const f16x8*)&TdS[lr * 136 + kc * 32 + quad * 8];
    const f16x8 bT1 = *(const f16x8*)&TdS[(16 + lr) * 136 + kc * 32 + quad * 8];
    acc2[0] = __builtin_amdgcn_mfma_f32_16x16x32_f16(aT, bT0, acc2[0], 0, 0, 0);
    acc2[1] = __builtin_amdgcn_mfma_f32_16x16x32_f16(aT, bT1, acc2[1], 0, 0, 0);
  }
  const int oo = w * 16 + quad * 4;
  float* shd = st_out + (blockIdx.x & (SH - 1)) * 256;
#pragma unroll
  for (int r = 0; r < 4; r++) {
    const float v0 = acc2[0][r] + bt[oo + r];
    const float v1 = acc2[1][r] + bt[oo + r];
    const size_t go = (size_t)(b * C + oo + r) * N + m0 + lr;
    T2h[go] = (_Float16)v0;
    T2h[go + 16] = (_Float16)v1;
    float s = v0 + v1, q = v0 * v0 + v1 * v1;
    s += __shfl_xor(s, 1, 64); q += __shfl_xor(q, 1, 64);
    s += __shfl_xor(s, 2, 64); q += __shfl_xor(q, 2, 64);
    s += __shfl_xor(s, 4, 64); q += __shfl_xor(q, 4, 64);
    s += __shfl_xor(s, 8, 64); q += __shfl_xor(q, 8, 64);
    if (lr == 0) {
      atomicAdd(&shd[oo + r], s);
      atomicAdd(&shd[128 + oo + r], q);
    }
  }
}

// ---------------------------------------------------------------------------
// Final apply (layer 3): Out = relu(bn(T2)) + H.  Coefficients read directly
// from sharded stats; H not rewritten (dead).
// grid 2048, 256 thr.
// ---------------------------------------------------------------------------
__global__ __launch_bounds__(256) void k_applyF(const _Float16* __restrict__ T2,
                                                const float* __restrict__ st,
                                                const float* __restrict__ gamma,
                                                const float* __restrict__ beta,
                                                const float* __restrict__ H,
                                                float* __restrict__ Out) {
  const int tid = threadIdx.x;
  const int f = (blockIdx.x * 256 + tid) * 4;
  const int c = (blockIdx.x >> 2) & 127;
  const float2 bc = bn_coef(st, c, gamma, beta);
  const f16x4 t = *(const f16x4*)&T2[f];
  const float4 h = *(const float4*)&H[f];
  float4 r;
  r.x = fmaxf((float)t[0] * bc.x + bc.y, 0.f) + h.x;
  r.y = fmaxf((float)t[1] * bc.x + bc.y, 0.f) + h.y;
  r.z = fmaxf((float)t[2] * bc.x + bc.y, 0.f) + h.z;
  r.w = fmaxf((float)t[3] * bc.x + bc.y, 0.f) + h.w;
  const int b = f >> 19;                // f / (C*N)
  const int rem = f & (C * N - 1);      // c*N + n
  *(float4*)&Out[(size_t)b * (4 * C * N) + rem] = r;
}

// ---------------------------------------------------------------------------
extern "C" void kernel_launch(void* const* d_in, const int* in_sizes, int n_in,
                              void* d_out, int out_size, void* d_ws, size_t ws_size,
                              hipStream_t stream) {
  const float* x    = (const float*)d_in[0];
  const int*   mask = (const int*)  d_in[1];
  const float* w1   = (const float*)d_in[2];
  const float* g1   = (const float*)d_in[3];
  const float* b1   = (const float*)d_in[4];
  const float* w2   = (const float*)d_in[5];
  const float* g2   = (const float*)d_in[6];
  const float* b2   = (const float*)d_in[7];
  const float* wqk  = (const float*)d_in[8];
  const float* wv   = (const float*)d_in[9];
  const float* bv   = (const float*)d_in[10];
  const float* wt   = (const float*)d_in[11];
  const float* bt   = (const float*)d_in[12];
  const float* sg   = (const float*)d_in[13];
  const float* sb   = (const float*)d_in[14];
  float* out = (float*)d_out;

  char* p = (char*)d_ws;
  auto alloc = [&](size_t bytes) { char* r = p; p += (bytes + 255) & ~(size_t)255; return r; };
  float*    H      = (float*)   alloc((size_t)B * C * N * 4);
  _Float16* T2a    = (_Float16*)alloc((size_t)B * C * N * 2);
  _Float16* T2b    = (_Float16*)alloc((size_t)B * C * N * 2);
  _Float16* QTc    = (_Float16*)alloc((size_t)B * N * 32 * 2);   // contiguous with
  _Float16* XVc    = (_Float16*)alloc((size_t)B * C * N * 2);    // XVc + bnstat:
  float*    bnstat = (float*)   alloc((size_t)6 * SH * 256 * 4); // one memset
  float2*   rowst  = (float2*)  alloc((size_t)B * N * 8);
  int*      psum   = (int*)     alloc((size_t)B * N * 4);
  int*      nvb    = (int*)     alloc(256);
  float*    xvp    = (float*)   alloc((size_t)B * C * 128 * 4);
  float*    xvi    = (float*)   alloc((size_t)B * C * 4);
  _Float16* WF     = (_Float16*)alloc((size_t)180224 * 2);
  (void)ws_size;
  _Float16* wf1  = WF;
  _Float16* wf2  = WF + 16384;
  _Float16* wfv  = WF + 32768;
  _Float16* wft  = WF + 98304;
  _Float16* wfqk = WF + 163840;
  auto st = [&](int k) { return bnstat + (size_t)k * SH * 256; };

  // ---- one-shot setup: weight convert, mask compaction, pad+stat zeroing ----
  k_wcvt<<<176, 256, 0, stream>>>(w1, w2, wv, wt, wqk, WF);
  k_mask<<<B, 1024, 0, stream>>>(mask, psum, nvb);
  hipMemsetAsync(QTc, 0,
                 (size_t)B * N * 32 * 2 + (size_t)B * C * N * 2 +
                 (size_t)6 * SH * 256 * 4,
                 stream);

  // ---- stem: gwm1 -> (BN1 fused into) gwm2 ----
  k_gwm<false><<<dim3(64, 2, B), 512, 0, stream>>>(wf1, x, nullptr, nullptr, nullptr,
                                                   T2a, st(0));
  k_gwm<true><<<dim3(64, 2, B), 512, 0, stream>>>(wf2, T2a, st(0), g1, b1, T2b, st(1));

  // ---- 4 chained offset-attention layers ----
  for (int L = 0; L < 4; L++) {
    if (L == 0)
      k_qvF<false><<<dim3(128, B), 256, 0, stream>>>(
          wfv, wfqk, T2b, st(1), g2, b2, H, nullptr, bv, mask, psum, XVc, QTc, xvp);
    else
      k_qvF<true><<<dim3(128, B), 256, 0, stream>>>(
          wfv + (size_t)L * 16384, wfqk + (size_t)L * 4096, T2a, st(1 + L),
          sg + (L - 1) * C, sb + (L - 1) * C, H, out + (size_t)(L - 1) * C * N,
          bv + L * C, mask, psum, XVc, QTc, xvp);
    k_sm<<<dim3(257, B), 512, 0, stream>>>(QTc, nvb, xvp, xvi, rowst);
    k_pv<<<dim3(128, B), 512, 0, stream>>>(QTc, XVc, wft + (size_t)L * 16384, H, mask,
                                           psum, rowst, nvb, xvi, bt + L * C, T2a,
                                           st(2 + L));
  }
  k_applyF<<<2048, 256, 0, stream>>>(T2a, st(5), sg + 3 * C, sb + 3 * C, H,
                                     out + (size_t)3 * C * N);
}